// Round 9
// baseline (252.065 us; speedup 1.0000x reference)
//
#include <hip/hip_runtime.h>
#include <math.h>

#define B_      4
#define L_      2048
#define IN_DIM  128
#define D_MODEL 256
#define OUT_DIM 128
#define D_STATE 16
#define D_INNER 768
#define NHEADS  256
#define HEADDIM 3
#define CONV_DIM 800
#define D_IN_PROJ 1824
#define DT_START (D_INNER + CONV_DIM)   // 1568

#define SCAN_NC 32
#define SCAN_CL 64
#define LPAD    2051        // L_ + 3 padded rows (row0 = left pad, rows 2049/2050 = right pad)

typedef short  short8 __attribute__((ext_vector_type(8)));
typedef float  f32x4  __attribute__((ext_vector_type(4)));

__device__ __forceinline__ unsigned short f2bf(float f) {
    unsigned int u = __float_as_uint(f);
    u = (u + 0x7fffu + ((u >> 16) & 1u)) >> 16;     // RN-to-even
    return (unsigned short)u;
}
__device__ __forceinline__ float bf2f(unsigned short h) {
    return __uint_as_float(((unsigned int)h) << 16);
}

// ---------------------------------------------------------------------------
// prep_all: ONE launch for ALL weight/input prep (early + late).
// ---------------------------------------------------------------------------
__global__ __launch_bounds__(256) void prep_all_kernel(
    unsigned short* __restrict__ xh, unsigned short* __restrict__ xl,
    const float* __restrict__ cw, unsigned short* __restrict__ cwh,
    unsigned short* __restrict__ cwl,
    const float* __restrict__ x,
    const float* __restrict__ ipsrc, unsigned short* __restrict__ ipwh,
    unsigned short* __restrict__ ipwl,
    const float* __restrict__ cow, unsigned short* __restrict__ cowh,
    unsigned short* __restrict__ th,
    const float* __restrict__ mosrc, unsigned short* __restrict__ mowh,
    unsigned short* __restrict__ mowl)
{
    __shared__ float tile[32][33];
    int bid = blockIdx.x;
    if (bid < 6) {
        int t = bid * 256 + threadIdx.x;
        int n = B_ * 3 * IN_DIM;
        if (t < n) {
            int ch = t % IN_DIM, rb = t / IN_DIM;
            int b = rb / 3, ri = rb % 3;
            int row = (ri == 0) ? 0 : (ri == 1) ? (L_ + 1) : (L_ + 2);
            size_t off = ((size_t)b * LPAD + row) * IN_DIM + ch;
            xh[off] = 0; xl[off] = 0;
        }
    } else if (bid < 518) {
        int t = (bid - 6) * 256 + threadIdx.x;   // 256*512
        if (t < D_MODEL * 512) {
            int o = t >> 9, kk = t & 511;
            int k = kk >> 7, i = kk & 127;
            float v = cw[((size_t)o * IN_DIM + i) * 4 + k];
            unsigned short h = f2bf(v);
            cwh[t] = h; cwl[t] = f2bf(v - bf2f(h));
        }
    } else if (bid < 1542) {
        int tid = bid - 518;                     // 0..1023
        int b = tid >> 8;
        int l0 = (tid & 63) * 32, i0 = ((tid >> 6) & 3) * 32;
        int tx = threadIdx.x & 31, ty = threadIdx.x >> 5;   // ty 0..7
        const float* xb = x + (size_t)b * IN_DIM * L_;
        #pragma unroll
        for (int r = 0; r < 4; ++r)
            tile[ty + r * 8][tx] = xb[(size_t)(i0 + ty + r * 8) * L_ + l0 + tx];
        __syncthreads();
        #pragma unroll
        for (int r = 0; r < 4; ++r) {
            int l = l0 + ty + r * 8;
            float v = tile[tx][ty + r * 8];                  // x[b][i0+tx][l]
            size_t off = ((size_t)b * LPAD + l + 1) * IN_DIM + i0 + tx;
            unsigned short h = f2bf(v);
            xh[off] = h;
            xl[off] = f2bf(v - bf2f(h));
        }
    } else if (bid < 1998) {
        int tid = bid - 1542;                    // 0..455, grid (57 n, 8 k)
        int n0 = (tid % 57) * 32, k0 = (tid / 57) * 32;
        const int K = D_MODEL, N = D_IN_PROJ;
        int tx = threadIdx.x & 31, ty = threadIdx.x >> 5;
        #pragma unroll
        for (int r = 0; r < 4; ++r)
            tile[ty + r * 8][tx] = ipsrc[(size_t)(k0 + ty + r * 8) * N + n0 + tx];
        __syncthreads();
        #pragma unroll
        for (int r = 0; r < 4; ++r) {
            int n = n0 + ty + r * 8;
            float v = tile[tx][ty + r * 8];
            unsigned short h = f2bf(v);
            ipwh[(size_t)n * K + k0 + tx] = h;
            ipwl[(size_t)n * K + k0 + tx] = f2bf(v - bf2f(h));
        }
    } else if (bid < 2510) {
        int t = (bid - 1998) * 256 + threadIdx.x;  // 128*1024
        if (t < OUT_DIM * 1024) {
            int o = t >> 10, kk = t & 1023;
            int k = kk >> 8, c = kk & 255;
            cowh[t] = f2bf(cow[((size_t)o * D_MODEL + c) * 4 + k]);
        }
    } else if (bid < 2522) {
        int t = (bid - 2510) * 256 + threadIdx.x;
        int n = B_ * 3 * D_MODEL;
        if (t < n) {
            int ch = t % D_MODEL, rb = t / D_MODEL;
            int b = rb / 3, ri = rb % 3;
            int row = (ri == 0) ? 0 : (ri == 1) ? (L_ + 1) : (L_ + 2);
            size_t off = ((size_t)b * LPAD + row) * D_MODEL + ch;
            th[off] = 0;
        }
    } else {
        int tid = bid - 2522;                     // 0..191, grid (8 n, 24 k)
        int n0 = (tid & 7) * 32, k0 = (tid >> 3) * 32;
        const int K = D_INNER, N = D_MODEL;
        int tx = threadIdx.x & 31, ty = threadIdx.x >> 5;
        #pragma unroll
        for (int r = 0; r < 4; ++r)
            tile[ty + r * 8][tx] = mosrc[(size_t)(k0 + ty + r * 8) * N + n0 + tx];
        __syncthreads();
        #pragma unroll
        for (int r = 0; r < 4; ++r) {
            int n = n0 + ty + r * 8;
            float v = tile[tx][ty + r * 8];
            unsigned short h = f2bf(v);
            mowh[(size_t)n * K + k0 + tx] = h;
            mowl[(size_t)n * K + k0 + tx] = f2bf(v - bf2f(h));
        }
    }
}

// ---------------------------------------------------------------------------
// in_proj GEMM, selective precision (unchanged; ~4 blocks/CU -> TLP covers).
// ---------------------------------------------------------------------------
__global__ __launch_bounds__(256) void gemm_ip2_kernel(
    const unsigned short* __restrict__ Ah, const unsigned short* __restrict__ Al,
    const unsigned short* __restrict__ Bh, const unsigned short* __restrict__ Bl,
    float* __restrict__ C, int M, int N, int K)
{
    __shared__ __align__(16) unsigned short AsH[128][40];
    __shared__ __align__(16) unsigned short AsL[128][40];
    __shared__ __align__(16) unsigned short BsH[128][40];
    __shared__ __align__(16) unsigned short BsL[128][40];

    int m0 = blockIdx.y * 128, n0 = blockIdx.x * 128;
    int t = threadIdx.x;
    int wid = t >> 6, lane = t & 63;
    int wm = (wid >> 1) * 64, wn = (wid & 1) * 64;
    int fr = lane & 15, fq = lane >> 4;
    bool full = (n0 + 127 >= DT_START);

    f32x4 z4 = {0.f, 0.f, 0.f, 0.f};
    f32x4 acc[4][4];
    #pragma unroll
    for (int i = 0; i < 4; ++i)
        #pragma unroll
        for (int j = 0; j < 4; ++j) acc[i][j] = z4;

    if (!full) {
        for (int k0 = 0; k0 < K; k0 += 32) {
            __syncthreads();
            #pragma unroll
            for (int p = 0; p < 2; ++p) {
                int idx = p * 256 + t;
                int row = idx >> 2, q = idx & 3;
                int koff = k0 + q * 8;
                *(float4*)&AsH[row][q * 8] =
                    *(const float4*)(Ah + (size_t)(m0 + row) * K + koff);
                int n = n0 + row;
                *(float4*)&BsH[row][q * 8] =
                    *(const float4*)(Bh + (size_t)n * K + koff);
            }
            __syncthreads();

            short8 ah[4], bh[4];
            #pragma unroll
            for (int i = 0; i < 4; ++i) {
                ah[i] = *(const short8*)&AsH[wm + i * 16 + fr][fq * 8];
                bh[i] = *(const short8*)&BsH[wn + i * 16 + fr][fq * 8];
            }
            #pragma unroll
            for (int i = 0; i < 4; ++i)
                #pragma unroll
                for (int j = 0; j < 4; ++j)
                    acc[i][j] = __builtin_amdgcn_mfma_f32_16x16x32_bf16(
                        ah[i], bh[j], acc[i][j], 0, 0, 0);
        }
    } else {
        for (int k0 = 0; k0 < K; k0 += 32) {
            __syncthreads();
            #pragma unroll
            for (int p = 0; p < 2; ++p) {
                int idx = p * 256 + t;
                int row = idx >> 2, q = idx & 3;
                int koff = k0 + q * 8;
                *(float4*)&AsH[row][q * 8] =
                    *(const float4*)(Ah + (size_t)(m0 + row) * K + koff);
                *(float4*)&AsL[row][q * 8] =
                    *(const float4*)(Al + (size_t)(m0 + row) * K + koff);
                int n = n0 + row;
                float4 vbh = make_float4(0.f, 0.f, 0.f, 0.f), vbl = vbh;
                if (n < N) {
                    vbh = *(const float4*)(Bh + (size_t)n * K + koff);
                    vbl = *(const float4*)(Bl + (size_t)n * K + koff);
                }
                *(float4*)&BsH[row][q * 8] = vbh;
                *(float4*)&BsL[row][q * 8] = vbl;
            }
            __syncthreads();

            short8 ah[4], al[4], bh[4], bl[4];
            #pragma unroll
            for (int i = 0; i < 4; ++i) {
                ah[i] = *(const short8*)&AsH[wm + i * 16 + fr][fq * 8];
                al[i] = *(const short8*)&AsL[wm + i * 16 + fr][fq * 8];
                bh[i] = *(const short8*)&BsH[wn + i * 16 + fr][fq * 8];
                bl[i] = *(const short8*)&BsL[wn + i * 16 + fr][fq * 8];
            }
            #pragma unroll
            for (int i = 0; i < 4; ++i)
                #pragma unroll
                for (int j = 0; j < 4; ++j) {
                    acc[i][j] = __builtin_amdgcn_mfma_f32_16x16x32_bf16(
                        ah[i], bh[j], acc[i][j], 0, 0, 0);
                    acc[i][j] = __builtin_amdgcn_mfma_f32_16x16x32_bf16(
                        ah[i], bl[j], acc[i][j], 0, 0, 0);
                    acc[i][j] = __builtin_amdgcn_mfma_f32_16x16x32_bf16(
                        al[i], bh[j], acc[i][j], 0, 0, 0);
                }
        }
    }

    #pragma unroll
    for (int i = 0; i < 4; ++i) {
        int r0 = m0 + wm + i * 16 + fq * 4;
        #pragma unroll
        for (int j = 0; j < 4; ++j) {
            int cc = n0 + wn + j * 16 + fr;
            if (cc < N) {
                #pragma unroll
                for (int r = 0; r < 4; ++r)
                    C[(size_t)(r0 + r) * N + cc] = acc[i][j][r];
            }
        }
    }
}

// ---------------------------------------------------------------------------
// conv_in as GEMM, 64x128 tile -> grid (2,128) = 256 blocks (fills all CUs).
// Register-prefetch pipelined; K-step accumulation order identical.
// ---------------------------------------------------------------------------
__global__ __launch_bounds__(256) void gemm_ci_kernel(
    const unsigned short* __restrict__ Ah, const unsigned short* __restrict__ Al,
    const unsigned short* __restrict__ Bh, const unsigned short* __restrict__ Bl,
    const float* __restrict__ bias,
    unsigned short* __restrict__ Ch, unsigned short* __restrict__ Cl)
{
    const int K = 512;
    __shared__ __align__(16) unsigned short AsH[64][40];
    __shared__ __align__(16) unsigned short AsL[64][40];
    __shared__ __align__(16) unsigned short BsH[128][40];
    __shared__ __align__(16) unsigned short BsL[128][40];

    int m0 = blockIdx.y * 64, n0 = blockIdx.x * 128;
    int b = m0 >> 11;
    size_t abase = ((size_t)b * LPAD + (m0 & 2047)) * IN_DIM;
    int t = threadIdx.x;
    int wid = t >> 6, lane = t & 63;
    int wm = (wid >> 1) * 32, wn = (wid & 1) * 64;
    int fr = lane & 15, fq = lane >> 4;
    int rr = t >> 2, q = t & 3;

    f32x4 z4 = {0.f, 0.f, 0.f, 0.f};
    f32x4 acc[2][4];
    #pragma unroll
    for (int i = 0; i < 2; ++i)
        #pragma unroll
        for (int j = 0; j < 4; ++j) acc[i][j] = z4;

    float4 rAh, rAl, rBh0, rBh1, rBl0, rBl1;
    auto ld = [&](int k0) {
        int koff = k0 + q * 8;
        rAh = *(const float4*)(Ah + abase + (size_t)rr * IN_DIM + koff);
        rAl = *(const float4*)(Al + abase + (size_t)rr * IN_DIM + koff);
        rBh0 = *(const float4*)(Bh + (size_t)(n0 + rr) * K + koff);
        rBh1 = *(const float4*)(Bh + (size_t)(n0 + rr + 64) * K + koff);
        rBl0 = *(const float4*)(Bl + (size_t)(n0 + rr) * K + koff);
        rBl1 = *(const float4*)(Bl + (size_t)(n0 + rr + 64) * K + koff);
    };
    ld(0);

    for (int k0 = 0; k0 < K; k0 += 32) {
        __syncthreads();
        *(float4*)&AsH[rr][q * 8] = rAh;
        *(float4*)&AsL[rr][q * 8] = rAl;
        *(float4*)&BsH[rr][q * 8] = rBh0;
        *(float4*)&BsH[rr + 64][q * 8] = rBh1;
        *(float4*)&BsL[rr][q * 8] = rBl0;
        *(float4*)&BsL[rr + 64][q * 8] = rBl1;
        __syncthreads();
        if (k0 + 32 < K) ld(k0 + 32);

        short8 ah[2], al[2], bh[4], bl[4];
        #pragma unroll
        for (int i = 0; i < 2; ++i) {
            ah[i] = *(const short8*)&AsH[wm + i * 16 + fr][fq * 8];
            al[i] = *(const short8*)&AsL[wm + i * 16 + fr][fq * 8];
        }
        #pragma unroll
        for (int j = 0; j < 4; ++j) {
            bh[j] = *(const short8*)&BsH[wn + j * 16 + fr][fq * 8];
            bl[j] = *(const short8*)&BsL[wn + j * 16 + fr][fq * 8];
        }
        #pragma unroll
        for (int i = 0; i < 2; ++i)
            #pragma unroll
            for (int j = 0; j < 4; ++j) {
                acc[i][j] = __builtin_amdgcn_mfma_f32_16x16x32_bf16(
                    ah[i], bh[j], acc[i][j], 0, 0, 0);
                acc[i][j] = __builtin_amdgcn_mfma_f32_16x16x32_bf16(
                    ah[i], bl[j], acc[i][j], 0, 0, 0);
                acc[i][j] = __builtin_amdgcn_mfma_f32_16x16x32_bf16(
                    al[i], bh[j], acc[i][j], 0, 0, 0);
            }
    }

    #pragma unroll
    for (int i = 0; i < 2; ++i) {
        int r0 = m0 + wm + i * 16 + fq * 4;
        #pragma unroll
        for (int j = 0; j < 4; ++j) {
            int cc = n0 + wn + j * 16 + fr;
            float bc = bias[cc];
            #pragma unroll
            for (int r = 0; r < 4; ++r) {
                float v = acc[i][j][r] + bc;
                unsigned short h = f2bf(v);
                size_t off = (size_t)(r0 + r) * D_MODEL + cc;
                Ch[off] = h;
                Cl[off] = f2bf(v - bf2f(h));
            }
        }
    }
}

// ---------------------------------------------------------------------------
// gemm_mog2: FUSED gate+RMSNorm+mamba_out on gemm_mo's PROVEN skeleton
// (64x128 tile, 256 blocks, register prefetch). Per K-step: load y/z (same
// addresses the old A-load hit in yb), gate+quantize in regs, write the 16B
// A-fragment where the old stage wrote. ss accumulated across the K-loop
// (per-thread 192 cols -> quad shfl reduce); rs applied in fp32 epilogue
// (commutes with GEMM; validated in R7). Kills gate_norm + yb round-trip.
// R7 failure-mode fixes: no full-K A in LDS (18.7KB total), mow staged once
// per 64 rows not per 16, 8 MFMA per stage cycle, all-CU grid.
// ---------------------------------------------------------------------------
__global__ __launch_bounds__(256) void gemm_mog2_kernel(
    const float* __restrict__ ybuf, const float* __restrict__ zx,
    const float* __restrict__ norm_w,
    const unsigned short* __restrict__ Bh,   // mow [256][768]
    unsigned short* __restrict__ Ch)         // tmpP padded bf16
{
    const int K = D_INNER;
    __shared__ __align__(16) unsigned short As[64][40];
    __shared__ __align__(16) unsigned short Bs[128][40];
    __shared__ __align__(16) float nws[768];
    __shared__ float rs_l[64];

    int m0 = blockIdx.y * 64, n0 = blockIdx.x * 128;
    int t = threadIdx.x;
    int wid = t >> 6, lane = t & 63;
    int wm = (wid >> 1) * 32, wn = (wid & 1) * 64;
    int fr = lane & 15, fq = lane >> 4;
    int rr = t >> 2, q = t & 3;

    // stage norm_w (768 floats, 3KB)
    if (t < 192) *(float4*)&nws[t * 4] = *(const float4*)&norm_w[t * 4];

    f32x4 z4 = {0.f, 0.f, 0.f, 0.f};
    f32x4 acc[2][4];
    #pragma unroll
    for (int i = 0; i < 2; ++i)
        #pragma unroll
        for (int j = 0; j < 4; ++j) acc[i][j] = z4;

    const float* yrow = ybuf + (size_t)(m0 + rr) * D_INNER;
    const float* zrow = zx + (size_t)(m0 + rr) * D_IN_PROJ;

    float ss = 0.f;
    unsigned int pk0, pk1, pk2, pk3;
    float4 rB0, rB1;
    auto ldg = [&](int k0) {
        int koff = k0 + q * 8;
        float4 y0 = *(const float4*)(yrow + koff);
        float4 y1 = *(const float4*)(yrow + koff + 4);
        float4 zv0 = *(const float4*)(zrow + koff);
        float4 zv1 = *(const float4*)(zrow + koff + 4);
        rB0 = *(const float4*)(Bh + (size_t)(n0 + rr) * K + koff);
        rB1 = *(const float4*)(Bh + (size_t)(n0 + rr + 64) * K + koff);
        float4 nw0 = *(const float4*)&nws[koff];
        float4 nw1 = *(const float4*)&nws[koff + 4];
        float v0 = y0.x * (zv0.x / (1.f + expf(-zv0.x)));
        float v1 = y0.y * (zv0.y / (1.f + expf(-zv0.y)));
        float v2 = y0.z * (zv0.z / (1.f + expf(-zv0.z)));
        float v3 = y0.w * (zv0.w / (1.f + expf(-zv0.w)));
        float v4 = y1.x * (zv1.x / (1.f + expf(-zv1.x)));
        float v5 = y1.y * (zv1.y / (1.f + expf(-zv1.y)));
        float v6 = y1.z * (zv1.z / (1.f + expf(-zv1.z)));
        float v7 = y1.w * (zv1.w / (1.f + expf(-zv1.w)));
        ss += v0*v0 + v1*v1 + v2*v2 + v3*v3 + v4*v4 + v5*v5 + v6*v6 + v7*v7;
        pk0 = (unsigned int)f2bf(v0 * nw0.x) | ((unsigned int)f2bf(v1 * nw0.y) << 16);
        pk1 = (unsigned int)f2bf(v2 * nw0.z) | ((unsigned int)f2bf(v3 * nw0.w) << 16);
        pk2 = (unsigned int)f2bf(v4 * nw1.x) | ((unsigned int)f2bf(v5 * nw1.y) << 16);
        pk3 = (unsigned int)f2bf(v6 * nw1.z) | ((unsigned int)f2bf(v7 * nw1.w) << 16);
    };
    __syncthreads();        // nws visible before ldg reads it
    ldg(0);

    for (int k0 = 0; k0 < K; k0 += 32) {
        __syncthreads();
        {
            unsigned int* ap = (unsigned int*)&As[rr][q * 8];
            ap[0] = pk0; ap[1] = pk1; ap[2] = pk2; ap[3] = pk3;
        }
        *(float4*)&Bs[rr][q * 8] = rB0;
        *(float4*)&Bs[rr + 64][q * 8] = rB1;
        __syncthreads();
        if (k0 + 32 < K) ldg(k0 + 32);

        short8 ah[2], bh[4];
        #pragma unroll
        for (int i = 0; i < 2; ++i)
            ah[i] = *(const short8*)&As[wm + i * 16 + fr][fq * 8];
        #pragma unroll
        for (int j = 0; j < 4; ++j)
            bh[j] = *(const short8*)&Bs[wn + j * 16 + fr][fq * 8];
        #pragma unroll
        for (int i = 0; i < 2; ++i)
            #pragma unroll
            for (int j = 0; j < 4; ++j)
                acc[i][j] = __builtin_amdgcn_mfma_f32_16x16x32_bf16(
                    ah[i], bh[j], acc[i][j], 0, 0, 0);
    }

    // rs: quad-reduce ss (4 lanes per row), rsqrt, share via LDS
    ss += __shfl_xor(ss, 1);
    ss += __shfl_xor(ss, 2);
    if ((lane & 3) == 0)
        rs_l[rr] = rsqrtf(ss * (1.f / D_INNER) + 1e-5f);
    __syncthreads();

    int b = m0 >> 11;
    #pragma unroll
    for (int i = 0; i < 2; ++i) {
        int rl0 = wm + i * 16 + fq * 4;
        #pragma unroll
        for (int j = 0; j < 4; ++j) {
            int cc = n0 + wn + j * 16 + fr;
            #pragma unroll
            for (int r = 0; r < 4; ++r) {
                int rl = rl0 + r;
                float v = acc[i][j][r] * rs_l[rl];
                int l = (m0 + rl) & 2047;
                size_t off = ((size_t)b * LPAD + l + 1) * D_MODEL + cc;
                Ch[off] = f2bf(v);
            }
        }
    }
}

// ---------------------------------------------------------------------------
// conv_out as GEMM, 64x64 tile -> grid (2,128) = 256 blocks.
// LDS-staged epilogue: stores 64B-contiguous along L.
// ---------------------------------------------------------------------------
__global__ __launch_bounds__(256) void gemm_co_kernel(
    const unsigned short* __restrict__ Ah, const unsigned short* __restrict__ Bh,
    float* __restrict__ out)
{
    const int K = 1024;
    __shared__ __align__(16) unsigned short AsH[64][40];
    __shared__ __align__(16) unsigned short BsH[64][40];
    __shared__ __align__(16) float outT[64][68];   // [cc_local][lr_local]

    int m0 = blockIdx.y * 64, n0 = blockIdx.x * 64;
    int b = m0 >> 11, l0t = m0 & 2047;
    size_t abase = ((size_t)b * LPAD + l0t) * D_MODEL;
    int t = threadIdx.x;
    int wid = t >> 6, lane = t & 63;
    int wm = (wid >> 1) * 32, wn = (wid & 1) * 32;
    int fr = lane & 15, fq = lane >> 4;
    int rr = t >> 2, q = t & 3;

    f32x4 z4 = {0.f, 0.f, 0.f, 0.f};
    f32x4 acc[2][2];
    #pragma unroll
    for (int i = 0; i < 2; ++i)
        #pragma unroll
        for (int j = 0; j < 2; ++j) acc[i][j] = z4;

    float4 rA, rB;
    auto ld = [&](int k0) {
        int koff = k0 + q * 8;
        rA = *(const float4*)(Ah + abase + (size_t)rr * D_MODEL + koff);
        rB = *(const float4*)(Bh + (size_t)(n0 + rr) * K + koff);
    };
    ld(0);

    for (int k0 = 0; k0 < K; k0 += 32) {
        __syncthreads();
        *(float4*)&AsH[rr][q * 8] = rA;
        *(float4*)&BsH[rr][q * 8] = rB;
        __syncthreads();
        if (k0 + 32 < K) ld(k0 + 32);

        short8 ah[2], bh[2];
        #pragma unroll
        for (int i = 0; i < 2; ++i)
            ah[i] = *(const short8*)&AsH[wm + i * 16 + fr][fq * 8];
        #pragma unroll
        for (int j = 0; j < 2; ++j)
            bh[j] = *(const short8*)&BsH[wn + j * 16 + fr][fq * 8];
        #pragma unroll
        for (int i = 0; i < 2; ++i)
            #pragma unroll
            for (int j = 0; j < 2; ++j)
                acc[i][j] = __builtin_amdgcn_mfma_f32_16x16x32_bf16(
                    ah[i], bh[j], acc[i][j], 0, 0, 0);
    }

    // epilogue: transpose through LDS; stores 64B-contiguous along L
    #pragma unroll
    for (int i = 0; i < 2; ++i)
        #pragma unroll
        for (int j = 0; j < 2; ++j)
            *(float4*)&outT[wn + j * 16 + fr][wm + i * 16 + fq * 4] =
                make_float4(acc[i][j][0], acc[i][j][1],
                            acc[i][j][2], acc[i][j][3]);
    __syncthreads();
    #pragma unroll
    for (int e = 0; e < 4; ++e) {
        int idx = e * 256 + t;
        int rowl = idx >> 4, colp = (idx & 15) * 4;
        float* dst = out + ((size_t)(b * OUT_DIM + n0 + rowl)) * L_ + l0t + colp;
        *(float4*)dst = *(const float4*)&outT[rowl][colp];
    }
}

// ---------------------------------------------------------------------------
// K4: causal depthwise conv + bias + SiLU. 8 l-values per thread.
// ---------------------------------------------------------------------------
__global__ __launch_bounds__(256) void dwconv_kernel(
    const float* __restrict__ zx, const float* __restrict__ w,
    const float* __restrict__ bias, float* __restrict__ xBCs)
{
    int idx = blockIdx.x * 256 + threadIdx.x;   // over B * L/8 * 800
    int c   = idx % CONV_DIM;
    int bl8 = idx / CONV_DIM;
    int b  = bl8 >> 8;               // L/8 = 256
    int l0 = (bl8 & 255) * 8;
    float4 wv = *(const float4*)&w[c * 4];
    float bi = bias[c];
    const float* base = zx + ((size_t)(b * L_ + l0)) * D_IN_PROJ + D_INNER + c;
    float r[11];
    #pragma unroll
    for (int k = 0; k < 11; ++k) {
        int l = l0 - 3 + k;
        r[k] = (l >= 0) ? base[(ptrdiff_t)(k - 3) * D_IN_PROJ] : 0.f;
    }
    #pragma unroll
    for (int i = 0; i < 8; ++i) {
        float acc = bi;
        acc = fmaf(r[i + 0], wv.x, acc);
        acc = fmaf(r[i + 1], wv.y, acc);
        acc = fmaf(r[i + 2], wv.z, acc);
        acc = fmaf(r[i + 3], wv.w, acc);
        float s = acc / (1.f + expf(-acc));
        xBCs[((size_t)(b * L_ + l0 + i)) * CONV_DIM + c] = s;
    }
}

// ---------------------------------------------------------------------------
// XCD-locality swizzle: all 32 hg blocks of one (b,c) share bid%8 -> same XCD
// bid = (bc>>3)<<8 | hg<<3 | (bc&7);  bc = b*32+c.
// ---------------------------------------------------------------------------
__device__ __forceinline__ void scan_decode(int bid, int& b, int& c, int& hg)
{
    int bcl = bid & 7;
    hg = (bid >> 3) & 31;
    int bc = ((bid >> 8) << 3) | bcl;
    c = bc & 31;
    b = bc >> 5;
}

// ---------------------------------------------------------------------------
// K5a+K5g merged: blocks 0..127 compute G[i][j] = C_i . B_j per (b,chunk)
// (bid%8 XCD mapping preserved); blocks 128.. run chunk-local state build.
// ---------------------------------------------------------------------------
__global__ __launch_bounds__(512) void scan_local2g(
    const float* __restrict__ xBCs, const float* __restrict__ zx,
    const float* __restrict__ dt_bias, const float* __restrict__ A_log,
    float* __restrict__ Sloc, float* __restrict__ prodA,
    float* __restrict__ dtb, float* __restrict__ G)
{
    int bid = blockIdx.x;
    int t = threadIdx.x;
    if (bid < 128) {
        // ---- gmat part (uses threads 0..255) ----
        __shared__ float Bs[64][16];
        __shared__ float Csg[64][16];
        int c = bid & 31, b = bid >> 5;
        int row0 = b * L_ + c * SCAN_CL;
        if (t < 256) {
            int j = t >> 2, q = t & 3;
            const float* r = xBCs + (size_t)(row0 + j) * CONV_DIM + D_INNER;
            *(float4*)&Bs[j][q * 4] = *(const float4*)(r + q * 4);
            *(float4*)&Csg[j][q * 4] = *(const float4*)(r + D_STATE + q * 4);
        }
        __syncthreads();
        if (t < 256) {
            int i = t >> 2, jq = t & 3;
            float4 c0 = *(const float4*)&Csg[i][0];
            float4 c1 = *(const float4*)&Csg[i][4];
            float4 c2 = *(const float4*)&Csg[i][8];
            float4 c3 = *(const float4*)&Csg[i][12];
            float dot[16];
            #pragma unroll
            for (int jj = 0; jj < 16; ++jj) {
                int j = jq * 16 + jj;
                float4 b0 = *(const float4*)&Bs[j][0];
                float4 b1 = *(const float4*)&Bs[j][4];
                float4 b2 = *(const float4*)&Bs[j][8];
                float4 b3 = *(const float4*)&Bs[j][12];
                float d = c0.x * b0.x + c0.y * b0.y + c0.z * b0.z + c0.w * b0.w;
                d = fmaf(c1.x, b1.x, d); d = fmaf(c1.y, b1.y, d);
                d = fmaf(c1.z, b1.z, d); d = fmaf(c1.w, b1.w, d);
                d = fmaf(c2.x, b2.x, d); d = fmaf(c2.y, b2.y, d);
                d = fmaf(c2.z, b2.z, d); d = fmaf(c2.w, b2.w, d);
                d = fmaf(c3.x, b3.x, d); d = fmaf(c3.y, b3.y, d);
                d = fmaf(c3.z, b3.z, d); d = fmaf(c3.w, b3.w, d);
                dot[jj] = d;
            }
            float* gout = G + ((size_t)bid * 64 + i) * 64 + jq * 16;
            #pragma unroll
            for (int q = 0; q < 4; ++q)
                *(float4*)(gout + q * 4) =
                    make_float4(dot[q*4], dot[q*4+1], dot[q*4+2], dot[q*4+3]);
        }
        return;
    }

    // ---- scan_local2 part ----
    __shared__ float  BsT[16][68];                      // [n][row], padded
    __shared__ __align__(16) float4 PkC4L[8][66];       // (pkx,pky,pkz,dtv)
    __shared__ float  UT[8][3][64];
    int b, c, hg;
    scan_decode(bid - 128, b, c, hg);
    int h0 = hg * 8;
    int row0 = b * L_ + c * SCAN_CL;

    if (t < 256) {   // B tile (coalesced)
        int j = t >> 2, q = t & 3;
        const float* r = xBCs + (size_t)(row0 + j) * CONV_DIM;
        float4 bv = *(const float4*)(r + D_INNER + q * 4);
        BsT[q*4+0][j] = bv.x; BsT[q*4+1][j] = bv.y;
        BsT[q*4+2][j] = bv.z; BsT[q*4+3][j] = bv.w;
    }
    {   // Pk staging: one entry per thread; fused softplus; single b128 write
        int hh = t & 7, j = t >> 3;
        float v = zx[(size_t)(row0 + j) * D_IN_PROJ + DT_START + h0 + hh]
                  + dt_bias[h0 + hh];
        float dtv = (v > 20.f) ? v : log1pf(expf(v));
        dtb[(size_t)(row0 + j) * NHEADS + h0 + hh] = dtv;   // spill for scan_final2
        const float* xr = xBCs + (size_t)(row0 + j) * CONV_DIM + (h0 + hh) * 3;
        PkC4L[hh][j] = make_float4(dtv * xr[0], dtv * xr[1], dtv * xr[2], dtv);
    }
    __syncthreads();

    int wv = t >> 6, lane = t & 63;
    int hh = wv;
    int hhu = __builtin_amdgcn_readfirstlane(wv);
    int p = lane >> 4, n = lane & 15;
    int pc = (p < 3) ? p : 2;

    float4 own = PkC4L[hh][lane];
    float pkx = own.x, pky = own.y, pkz = own.z, pkw = own.w;
    float A = -__expf(A_log[h0 + hhu]);
    float cum = pkw * A;
    #pragma unroll
    for (int off = 1; off < 64; off <<= 1) {
        float sv = __shfl_up(cum, off);
        if (lane >= off) cum += sv;
    }
    float cum63 = __shfl(cum, 63);
    float wf = __expf(cum63 - cum);
    UT[hh][0][lane] = wf * pkx;
    UT[hh][1][lane] = wf * pky;
    UT[hh][2][lane] = wf * pkz;
    float state = 0.f;
    #pragma unroll
    for (int q = 0; q < 16; ++q) {
        float4 Bv = *(const float4*)&BsT[n][q * 4];
        float4 Uv = *(const float4*)&UT[hh][pc][q * 4];
        state = fmaf(Uv.x, Bv.x, state);
        state = fmaf(Uv.y, Bv.y, state);
        state = fmaf(Uv.z, Bv.z, state);
        state = fmaf(Uv.w, Bv.w, state);
    }
    size_t bh = (size_t)(b * NHEADS + h0 + hh);
    if (p < 3) Sloc[(bh * SCAN_NC + c) * 48 + p * 16 + n] = state;
    if (lane == 0) prodA[bh * SCAN_NC + c] = __expf(cum63);
}

// ---------------------------------------------------------------------------
// K5b: sequential prefix over chunks, in place on Sloc
// ---------------------------------------------------------------------------
__global__ __launch_bounds__(256) void scan_prefix_kernel(
    float* __restrict__ Sloc, const float* __restrict__ prodA)
{
    int wv   = blockIdx.x * 4 + (threadIdx.x >> 6);
    int lane = threadIdx.x & 63;
    int p = lane >> 4, n = lane & 15;
    bool act = (p < 3);
    int l48 = ((p < 3) ? p : 2) * 16 + n;
    size_t base = (size_t)wv * SCAN_NC;

    float cur = 0.f;
    for (int c = 0; c < SCAN_NC; ++c) {
        float s  = Sloc[(base + c) * 48 + l48];
        float pa = prodA[base + c];
        if (act) Sloc[(base + c) * 48 + l48] = cur;
        cur = fmaf(pa, cur, s);
    }
}

// ---------------------------------------------------------------------------
// K5c: chunk-matmul final scan (unchanged).
// ---------------------------------------------------------------------------
__global__ __launch_bounds__(512) void scan_final2(
    const float* __restrict__ xBCs, const float* __restrict__ dtb,
    const float* __restrict__ A_log, const float* __restrict__ Dp,
    const float* __restrict__ Sinit, const float* __restrict__ G,
    float* __restrict__ y)
{
    __shared__ __align__(16) float4 PkC4[8][67];  // slot(j)=j+(j>>4)
    __shared__ float XWx[8][64];                  // wj*pkx (broadcast reads)
    __shared__ float XWy[8][64];
    __shared__ float XWz[8][64];
    __shared__ __align__(16) float Cs[64][36];    // [row][n], stride 36
    union GsYsr {
        float gs[64][64];                         // G tile, XOR-swizzled cols
        float ysr[64][25];                        // epilogue buffer (aliased)
    };
    __shared__ __align__(16) GsYsr Us;
    int b, c, hg;
    scan_decode(blockIdx.x, b, c, hg);
    int h0 = hg * 8;
    int t = threadIdx.x;
    int row0 = b * L_ + c * SCAN_CL;

    {   // Pk staging: one (head,row) per thread, single b128 LDS write
        int hh = t & 7, j = t >> 3;
        float dtv = dtb[(size_t)(row0 + j) * NHEADS + h0 + hh];
        const float* xr = xBCs + (size_t)(row0 + j) * CONV_DIM + (h0 + hh) * 3;
        PkC4[hh][j + (j >> 4)] =
            make_float4(dtv * xr[0], dtv * xr[1], dtv * xr[2], dtv);
    }
    if (t < 256) {   // C tile: coalesced global float4, b128 LDS write
        int j = t >> 2, q = t & 3;
        const float* r = xBCs + (size_t)(row0 + j) * CONV_DIM + D_INNER + D_STATE;
        *(float4*)&Cs[j][q * 4] = *(const float4*)(r + q * 4);
    }
    {   // G staging: 1024 float4 coalesced global reads, XOR-swizzled store
        const float* Gsrc = G + (size_t)(b * SCAN_NC + c) * 4096;
        #pragma unroll
        for (int e = 0; e < 2; ++e) {
            int idx = e * 512 + t;              // float4 index 0..1023
            int row = idx >> 4, cq = (idx & 15) * 4;
            *(float4*)&Us.gs[row][cq ^ ((row & 7) << 2)] =
                *(const float4*)(Gsrc + (size_t)idx * 4);
        }
    }
    __syncthreads();

    int wv = t >> 6, lane = t & 63;
    int hh = wv;
    int hhu = __builtin_amdgcn_readfirstlane(wv);   // SGPR wave id
    int I = lane >> 4;
    int sw = (lane & 7) << 2;                       // Gs read swizzle

    float4 own = PkC4[hh][lane + (lane >> 4)];
    float pkx = own.x, pky = own.y, pkz = own.z, pkw = own.w;

    // wave-uniform scalar loads (SMEM pipe): Sin row, A, D
    const float* sinp = Sinit +
        ((size_t)(b * NHEADS + h0 + hhu) * SCAN_NC + c) * 48;
    float A = -__expf(A_log[h0 + hhu]);
    float Dh = Dp[h0 + hhu];

    float cum = pkw * A;
    #pragma unroll
    for (int off = 1; off < 64; off <<= 1) {
        float sv = __shfl_up(cum, off);
        if (lane >= off) cum += sv;
    }
    float e0 = __shfl(cum, 15);
    float e1 = __shfl(cum, 31);
    float e2 = __shfl(cum, 47);
    float e3 = __shfl(cum, 63);
    int ia = (I << 4) - 1;
    float AIr = __shfl(cum, ia < 0 ? 0 : ia);
    float AI = (I == 0) ? 0.f : AIr;
    float ri = __expf(cum - AI);
    float Eo = (I == 0) ? e0 : (I == 1) ? e1 : (I == 2) ? e2 : e3;
    float wj = __expf(Eo - cum);
    XWx[hh][lane] = wj * pkx;
    XWy[hh][lane] = wj * pky;
    XWz[hh][lane] = wj * pkz;
    PkC4[hh][lane + (lane >> 4)].w = cum;        // publish cum_j (wave-local)
    float S0 = (I > 0) ? __expf(AI - e0) : 0.f;
    float S1 = (I > 1) ? __expf(AI - e1) : 0.f;
    float S2 = (I > 2) ? __expf(AI - e2) : 0.f;
    float ecum = __expf(cum);

    // per-lane C row (4 conflict-free b128 LDS reads)
    float4 c0 = *(const float4*)&Cs[lane][0];
    float4 c1 = *(const float4*)&Cs[lane][4];
    float4 c2 = *(const float4*)&Cs[lane][8];
    float4 c3 = *(const float4*)&Cs[lane][12];

    // initial-state part: s_p = sum_n C[lane][n] * Sin[p][n]  (Sin uniform)
    float s0, s1, s2;
    {
        s0 = c0.x*sinp[0];  s0 = fmaf(c0.y,sinp[1],s0);  s0 = fmaf(c0.z,sinp[2],s0);  s0 = fmaf(c0.w,sinp[3],s0);
        s0 = fmaf(c1.x,sinp[4],s0);  s0 = fmaf(c1.y,sinp[5],s0);  s0 = fmaf(c1.z,sinp[6],s0);  s0 = fmaf(c1.w,sinp[7],s0);
        s0 = fmaf(c2.x,sinp[8],s0);  s0 = fmaf(c2.y,sinp[9],s0);  s0 = fmaf(c2.z,sinp[10],s0); s0 = fmaf(c2.w,sinp[11],s0);
        s0 = fmaf(c3.x,sinp[12],s0); s0 = fmaf(c3.y,sinp[13],s0); s0 = fmaf(c3.z,sinp[14],s0); s0 = fmaf(c3.w,sinp[15],s0);
        s1 = c0.x*sinp[16]; s1 = fmaf(c0.y,sinp[17],s1); s1 = fmaf(c0.z,sinp[18],s1); s1 = fmaf(c0.w,sinp[19],s1);
        s1 = fmaf(c1.x,sinp[20],s1); s1 = fmaf(c1.y,sinp[21],s1); s1 = fmaf(c1.z,sinp[22],s1); s1 = fmaf(c1.w,sinp[23],s1);
        s1 = fmaf(c2.x,sinp[24],s1); s1 = fmaf(c2.y,sinp[25],s1); s1 = fmaf(c2.z,sinp[26],s1); s1 = fmaf(c2.w,sinp[27],s1);
        s1 = fmaf(c3.x,sinp[28],s1); s1 = fmaf(c3.y,sinp[29],s1); s1 = fmaf(c3.z,sinp[30],s1); s1 = fmaf(c3.w,sinp[31],s1);
        s2 = c0.x*sinp[32]; s2 = fmaf(c0.y,sinp[33],s2); s2 = fmaf(c0.z,sinp[34],s2); s2 = fmaf(c0.w,sinp[35],s2);
        s2 = fmaf(c1.x,sinp[36],s2); s2 = fmaf(c1.y,sinp[37],s2); s2 = fmaf(c1.z,sinp[38],s2); s2 = fmaf(c1.w,sinp[39],s2);
        s2 = fmaf(c2.x,sinp[40],s2); s2 = fmaf(c2.y,sinp[41],s2); s2 = fmaf(c2.z,sinp[42],s2); s2 = fmaf(c2.w,sinp[43],s2);
        s2 = fmaf(c3.x,sinp[44],s2); s2 = fmaf(c3.y,sinp[45],s2); s2 = fmaf(c3.z,sinp[46],s2); s2 = fmaf(c3.w,sinp[47],s2);
    }

    // J < I blocks: t_J = sum_kk Gs[lane][16J+kk] * xw_kk ; acc += S_J * t_J
    float acc0 = 0.f, acc1 = 0.f, acc2 = 0.f;
    #pragma unroll
    for (int J = 0; J < 3; ++J) {
        float SJ = (J == 0) ? S0 : (J == 1) ? S1 : S2;
        float t0 = 0.f, t1 = 0.f, t2 = 0.f;
        #pragma unroll
        for (int q = 0; q < 4; ++q) {
            float4 g4 = *(const float4*)&Us.gs[lane][(J * 16 + q * 4) ^ sw];
            float4 ux = *(const float4*)&XWx[hh][J * 16 + q * 4];
            float4 uy = *(const float4*)&XWy[hh][J * 16 + q * 4];
            float4 uz = *(const float4*)&XWz[hh][J * 16 + q * 4];
            t0 = fmaf(g4.x, ux.x, t0); t1 = fmaf(g4.x, uy.x, t1); t2 = fmaf(g4.x, uz.x, t2);
            t0 = fmaf(g4.y, ux.y, t0); t1 = fmaf(g4.y, uy.y, t1); t2 = fmaf(g4.y, uz.y, t2);
            t0 = fmaf(g4.z, ux.z, t0); t1 = fmaf(g4.z, uy.z, t1); t2 = fmaf(g4.z, uz.z, t2);
            t0 = fmaf(g4.w, ux.w, t0); t1 = fmaf(g4.w, uy.w, t1); t2 = fmaf(g4.w, uz.w, t2);
        }
        acc0 = fmaf(SJ, t0, acc0);
        acc1 = fmaf(SJ, t1, acc1);
        acc2 = fmaf(SJ, t2, acc2);
    }

    // diagonal block (J == I): masked, exp(cum_i - cum_j) <= 1 always
    float d0 = 0.f, d1 = 0.f, d2 = 0.f;
    const float4* pkr = &PkC4[hh][I * 17];
    int lr = lane & 15;
    #pragma unroll
    for (int q = 0; q < 4; ++q) {
        float4 g4 = *(const float4*)&Us.gs[lane][((I << 4) + q * 4) ^ sw];
        #pragma unroll
        for (int k = 0; k < 4; ++k) {
            int kk = q * 4 + k;
            float4 p4 = pkr[kk];
            float gk = (k == 0) ? g4.x : (k == 1) ? g4.y : (k == 2) ? g4.z : g4.w;
            float e = __expf(cum - p4.w);
            float mg = (kk <= lr) ? e * gk : 0.f;
            d0 = fmaf(mg, p4.x, d0);
            d1 = fmaf(mg, p4.y, d1);
            d2 = fmaf(mg, p4.z, d2);
        }
    }

    float rdt = 1.0f / pkw;
    float y0 = fmaf(ri, acc0, d0) + fmaf(ecum, s0, Dh * (pkx * rdt));
    float y1 = fmaf(ri, acc1, d1) + fmaf(ecum, s1, Dh * (pky * rdt));
    float y2 = fmaf(ri, acc2, d2) + fmaf(ecum, s2, Dh * (pkz * rdt));

    __syncthreads();     // all waves done reading Gs before ysr aliases it
    {
        float* yr = &Us.ysr[lane][hh * 3];
        yr[0] = y0; yr[1] = y1; yr[2] = y2;
    }
    __syncthreads();

    {   // coalesced epilogue: 24 contiguous channels per row
        int i2 = t >> 3, q2 = t & 7;
        float* dst = y + (size_t)(row0 + i2) * D_INNER + hg * 24 + q2 * 3;
        dst[0] = Us.ysr[i2][q2 * 3 + 0];
        dst[1] = Us.ysr[i2][q2 * 3 + 1];
        dst[2] = Us.ysr[i2][q2 * 3 + 2];
    }
}

// ---------------------------------------------------------------------------
extern "C" void kernel_launch(void* const* d_in, const int* in_sizes, int n_in,
                              void* d_out, int out_size, void* d_ws, size_t ws_size,
                              hipStream_t stream)
{
    const float* x           = (const float*)d_in[0];
    const float* conv_w      = (const float*)d_in[1];
    const float* conv_b      = (const float*)d_in[2];
    const float* in_proj_w   = (const float*)d_in[3];
    const float* dw_conv_w   = (const float*)d_in[4];
    const float* dw_conv_b   = (const float*)d_in[5];
    const float* dt_bias     = (const float*)d_in[6];
    const float* A_log       = (const float*)d_in[7];
    const float* Dp          = (const float*)d_in[8];
    const float* norm_w      = (const float*)d_in[9];
    const float* mamba_out_w = (const float*)d_in[10];
    const float* out_conv_w  = (const float*)d_in[11];
    float* out = (float*)d_out;
    float* ws  = (float*)d_ws;

    // ---- workspace layout (floats; ws = 256 MiB, we use ~133 MB) ----
    float* S0   = ws;                        //  2,097,152  Gbuf+Sloc
    float* zx   = S0 + 2097152;              // 14,942,208  early: xT+cw / zx
    float* xBCs = zx + 14942208;             //  6,553,600  early: ipw / xBCs
    float* dtb  = xBCs + 6553600;            //  2,097,152  dtv spill
    float* ybuf = dtb + 2097152;             //  6,291,456  early: prodA+u / y
    float* tmpPf = ybuf + 6291456;           //  1,050,112  padded bf16 tmpP
    float* mowf  = tmpPf + 1050112;          //    196,608  mow hi+lo
    float* cowf  = mowf + 196608;            //     65,536  cow hi

    float* Gbuf = S0;                        // 524,288
    float* Sloc = S0 + 524288;               // 1,572,864

    unsigned short* xT_hi = (unsigned short*)zx;
    unsigned short* xT_lo = (unsigned short*)(zx + 525056);
    unsigned short* cw_hi = (unsigned short*)(zx + 1050112);
    unsigned short* cw_lo = (unsigned short*)(zx + 1115648);

    unsigned short* ipw_hi = (unsigned short*)xBCs;
    unsigned short* ipw_lo = (unsigned short*)(xBCs + 233472);

    float* prodA = ybuf;
    unsigned short* u_hi = (unsigned short*)(ybuf + 32768);
    unsigned short* u_lo = (unsigned short*)(ybuf + 32768 + 1048576);

    unsigned short* tmpP_hi = (unsigned short*)tmpPf;          // 2,100,224 ush
    unsigned short* mow_hi  = (unsigned short*)mowf;           //   196,608 ush
    unsigned short* mow_lo  = (unsigned short*)(mowf + 98304); //   196,608 ush
    unsigned short* cow_hi  = (unsigned short*)cowf;           //   131,072 ush

    // ---- 1. ALL prep (early + late weights) in ONE launch ----
    prep_all_kernel<<<2714, 256, 0, stream>>>(
        xT_hi, xT_lo, conv_w, cw_hi, cw_lo, x, in_proj_w, ipw_hi, ipw_lo,
        out_conv_w, cow_hi, tmpP_hi, mamba_out_w, mow_hi, mow_lo);

    // ---- 2. conv_in as GEMM (64x128 tiles, 256 blocks) ----
    gemm_ci_kernel<<<dim3(2, (B_ * L_) / 64), 256, 0, stream>>>(
        xT_hi, xT_lo, cw_hi, cw_lo, conv_b, u_hi, u_lo);

    // ---- 3. in_proj GEMM (selective precision) ----
    gemm_ip2_kernel<<<dim3((D_IN_PROJ + 127) / 128, (B_ * L_) / 128), 256, 0, stream>>>(
        u_hi, u_lo, ipw_hi, ipw_lo, zx, B_ * L_, D_IN_PROJ, D_MODEL);

    // ---- 4. elementwise + scan ----
    dwconv_kernel<<<(B_ * (L_ / 8) * CONV_DIM) / 256, 256, 0, stream>>>(
        zx, dw_conv_w, dw_conv_b, xBCs);
    scan_local2g<<<128 + B_ * SCAN_NC * (NHEADS / 8), 512, 0, stream>>>(
        xBCs, zx, dt_bias, A_log, Sloc, prodA, dtb, Gbuf);
    scan_prefix_kernel<<<(B_ * NHEADS) / 4, 256, 0, stream>>>(Sloc, prodA);
    scan_final2<<<B_ * SCAN_NC * (NHEADS / 8), 512, 0, stream>>>(
        xBCs, dtb, A_log, Dp, Sloc, Gbuf, ybuf);

    // ---- 5. FUSED gate+RMSNorm+mamba_out (64x128 tiles, 256 blocks) ----
    gemm_mog2_kernel<<<dim3(2, (B_ * L_) / 64), 256, 0, stream>>>(
        ybuf, zx, norm_w, mow_hi, tmpP_hi);

    // ---- 6. conv_out as GEMM (64x64 tiles, 256 blocks, coalesced stores) ----
    gemm_co_kernel<<<dim3(OUT_DIM / 64, (B_ * L_) / 64), 256, 0, stream>>>(
        tmpP_hi, cow_hi, out);
}

// Round 10
// 237.587 us; speedup vs baseline: 1.0609x; 1.0609x over previous
//
#include <hip/hip_runtime.h>
#include <math.h>

#define B_      4
#define L_      2048
#define IN_DIM  128
#define D_MODEL 256
#define OUT_DIM 128
#define D_STATE 16
#define D_INNER 768
#define NHEADS  256
#define HEADDIM 3
#define CONV_DIM 800
#define D_IN_PROJ 1824
#define DT_START (D_INNER + CONV_DIM)   // 1568

#define SCAN_NC 32
#define SCAN_CL 64
#define LPAD    2051        // L_ + 3 padded rows (row0 = left pad, rows 2049/2050 = right pad)

typedef short  short8 __attribute__((ext_vector_type(8)));
typedef float  f32x4  __attribute__((ext_vector_type(4)));

__device__ __forceinline__ unsigned short f2bf(float f) {
    unsigned int u = __float_as_uint(f);
    u = (u + 0x7fffu + ((u >> 16) & 1u)) >> 16;     // RN-to-even
    return (unsigned short)u;
}
__device__ __forceinline__ float bf2f(unsigned short h) {
    return __uint_as_float(((unsigned int)h) << 16);
}

// ---------------------------------------------------------------------------
// prep_all: ONE launch for ALL weight/input prep (early + late).
// ---------------------------------------------------------------------------
__global__ __launch_bounds__(256) void prep_all_kernel(
    unsigned short* __restrict__ xh, unsigned short* __restrict__ xl,
    const float* __restrict__ cw, unsigned short* __restrict__ cwh,
    unsigned short* __restrict__ cwl,
    const float* __restrict__ x,
    const float* __restrict__ ipsrc, unsigned short* __restrict__ ipwh,
    unsigned short* __restrict__ ipwl,
    const float* __restrict__ cow, unsigned short* __restrict__ cowh,
    unsigned short* __restrict__ th,
    const float* __restrict__ mosrc, unsigned short* __restrict__ mowh,
    unsigned short* __restrict__ mowl)
{
    __shared__ float tile[32][33];
    int bid = blockIdx.x;
    if (bid < 6) {
        int t = bid * 256 + threadIdx.x;
        int n = B_ * 3 * IN_DIM;
        if (t < n) {
            int ch = t % IN_DIM, rb = t / IN_DIM;
            int b = rb / 3, ri = rb % 3;
            int row = (ri == 0) ? 0 : (ri == 1) ? (L_ + 1) : (L_ + 2);
            size_t off = ((size_t)b * LPAD + row) * IN_DIM + ch;
            xh[off] = 0; xl[off] = 0;
        }
    } else if (bid < 518) {
        int t = (bid - 6) * 256 + threadIdx.x;   // 256*512
        if (t < D_MODEL * 512) {
            int o = t >> 9, kk = t & 511;
            int k = kk >> 7, i = kk & 127;
            float v = cw[((size_t)o * IN_DIM + i) * 4 + k];
            unsigned short h = f2bf(v);
            cwh[t] = h; cwl[t] = f2bf(v - bf2f(h));
        }
    } else if (bid < 1542) {
        int tid = bid - 518;                     // 0..1023
        int b = tid >> 8;
        int l0 = (tid & 63) * 32, i0 = ((tid >> 6) & 3) * 32;
        int tx = threadIdx.x & 31, ty = threadIdx.x >> 5;   // ty 0..7
        const float* xb = x + (size_t)b * IN_DIM * L_;
        #pragma unroll
        for (int r = 0; r < 4; ++r)
            tile[ty + r * 8][tx] = xb[(size_t)(i0 + ty + r * 8) * L_ + l0 + tx];
        __syncthreads();
        #pragma unroll
        for (int r = 0; r < 4; ++r) {
            int l = l0 + ty + r * 8;
            float v = tile[tx][ty + r * 8];                  // x[b][i0+tx][l]
            size_t off = ((size_t)b * LPAD + l + 1) * IN_DIM + i0 + tx;
            unsigned short h = f2bf(v);
            xh[off] = h;
            xl[off] = f2bf(v - bf2f(h));
        }
    } else if (bid < 1998) {
        int tid = bid - 1542;                    // 0..455, grid (57 n, 8 k)
        int n0 = (tid % 57) * 32, k0 = (tid / 57) * 32;
        const int K = D_MODEL, N = D_IN_PROJ;
        int tx = threadIdx.x & 31, ty = threadIdx.x >> 5;
        #pragma unroll
        for (int r = 0; r < 4; ++r)
            tile[ty + r * 8][tx] = ipsrc[(size_t)(k0 + ty + r * 8) * N + n0 + tx];
        __syncthreads();
        #pragma unroll
        for (int r = 0; r < 4; ++r) {
            int n = n0 + ty + r * 8;
            float v = tile[tx][ty + r * 8];
            unsigned short h = f2bf(v);
            ipwh[(size_t)n * K + k0 + tx] = h;
            ipwl[(size_t)n * K + k0 + tx] = f2bf(v - bf2f(h));
        }
    } else if (bid < 2510) {
        int t = (bid - 1998) * 256 + threadIdx.x;  // 128*1024
        if (t < OUT_DIM * 1024) {
            int o = t >> 10, kk = t & 1023;
            int k = kk >> 8, c = kk & 255;
            cowh[t] = f2bf(cow[((size_t)o * D_MODEL + c) * 4 + k]);
        }
    } else if (bid < 2522) {
        int t = (bid - 2510) * 256 + threadIdx.x;
        int n = B_ * 3 * D_MODEL;
        if (t < n) {
            int ch = t % D_MODEL, rb = t / D_MODEL;
            int b = rb / 3, ri = rb % 3;
            int row = (ri == 0) ? 0 : (ri == 1) ? (L_ + 1) : (L_ + 2);
            size_t off = ((size_t)b * LPAD + row) * D_MODEL + ch;
            th[off] = 0;
        }
    } else {
        int tid = bid - 2522;                     // 0..191, grid (8 n, 24 k)
        int n0 = (tid & 7) * 32, k0 = (tid >> 3) * 32;
        const int K = D_INNER, N = D_MODEL;
        int tx = threadIdx.x & 31, ty = threadIdx.x >> 5;
        #pragma unroll
        for (int r = 0; r < 4; ++r)
            tile[ty + r * 8][tx] = mosrc[(size_t)(k0 + ty + r * 8) * N + n0 + tx];
        __syncthreads();
        #pragma unroll
        for (int r = 0; r < 4; ++r) {
            int n = n0 + ty + r * 8;
            float v = tile[tx][ty + r * 8];
            unsigned short h = f2bf(v);
            mowh[(size_t)n * K + k0 + tx] = h;
            mowl[(size_t)n * K + k0 + tx] = f2bf(v - bf2f(h));
        }
    }
}

// ---------------------------------------------------------------------------
// in_proj GEMM, selective precision (unchanged; ~4 blocks/CU -> TLP covers).
// ---------------------------------------------------------------------------
__global__ __launch_bounds__(256) void gemm_ip2_kernel(
    const unsigned short* __restrict__ Ah, const unsigned short* __restrict__ Al,
    const unsigned short* __restrict__ Bh, const unsigned short* __restrict__ Bl,
    float* __restrict__ C, int M, int N, int K)
{
    __shared__ __align__(16) unsigned short AsH[128][40];
    __shared__ __align__(16) unsigned short AsL[128][40];
    __shared__ __align__(16) unsigned short BsH[128][40];
    __shared__ __align__(16) unsigned short BsL[128][40];

    int m0 = blockIdx.y * 128, n0 = blockIdx.x * 128;
    int t = threadIdx.x;
    int wid = t >> 6, lane = t & 63;
    int wm = (wid >> 1) * 64, wn = (wid & 1) * 64;
    int fr = lane & 15, fq = lane >> 4;
    bool full = (n0 + 127 >= DT_START);

    f32x4 z4 = {0.f, 0.f, 0.f, 0.f};
    f32x4 acc[4][4];
    #pragma unroll
    for (int i = 0; i < 4; ++i)
        #pragma unroll
        for (int j = 0; j < 4; ++j) acc[i][j] = z4;

    if (!full) {
        for (int k0 = 0; k0 < K; k0 += 32) {
            __syncthreads();
            #pragma unroll
            for (int p = 0; p < 2; ++p) {
                int idx = p * 256 + t;
                int row = idx >> 2, q = idx & 3;
                int koff = k0 + q * 8;
                *(float4*)&AsH[row][q * 8] =
                    *(const float4*)(Ah + (size_t)(m0 + row) * K + koff);
                int n = n0 + row;
                *(float4*)&BsH[row][q * 8] =
                    *(const float4*)(Bh + (size_t)n * K + koff);
            }
            __syncthreads();

            short8 ah[4], bh[4];
            #pragma unroll
            for (int i = 0; i < 4; ++i) {
                ah[i] = *(const short8*)&AsH[wm + i * 16 + fr][fq * 8];
                bh[i] = *(const short8*)&BsH[wn + i * 16 + fr][fq * 8];
            }
            #pragma unroll
            for (int i = 0; i < 4; ++i)
                #pragma unroll
                for (int j = 0; j < 4; ++j)
                    acc[i][j] = __builtin_amdgcn_mfma_f32_16x16x32_bf16(
                        ah[i], bh[j], acc[i][j], 0, 0, 0);
        }
    } else {
        for (int k0 = 0; k0 < K; k0 += 32) {
            __syncthreads();
            #pragma unroll
            for (int p = 0; p < 2; ++p) {
                int idx = p * 256 + t;
                int row = idx >> 2, q = idx & 3;
                int koff = k0 + q * 8;
                *(float4*)&AsH[row][q * 8] =
                    *(const float4*)(Ah + (size_t)(m0 + row) * K + koff);
                *(float4*)&AsL[row][q * 8] =
                    *(const float4*)(Al + (size_t)(m0 + row) * K + koff);
                int n = n0 + row;
                float4 vbh = make_float4(0.f, 0.f, 0.f, 0.f), vbl = vbh;
                if (n < N) {
                    vbh = *(const float4*)(Bh + (size_t)n * K + koff);
                    vbl = *(const float4*)(Bl + (size_t)n * K + koff);
                }
                *(float4*)&BsH[row][q * 8] = vbh;
                *(float4*)&BsL[row][q * 8] = vbl;
            }
            __syncthreads();

            short8 ah[4], al[4], bh[4], bl[4];
            #pragma unroll
            for (int i = 0; i < 4; ++i) {
                ah[i] = *(const short8*)&AsH[wm + i * 16 + fr][fq * 8];
                al[i] = *(const short8*)&AsL[wm + i * 16 + fr][fq * 8];
                bh[i] = *(const short8*)&BsH[wn + i * 16 + fr][fq * 8];
                bl[i] = *(const short8*)&BsL[wn + i * 16 + fr][fq * 8];
            }
            #pragma unroll
            for (int i = 0; i < 4; ++i)
                #pragma unroll
                for (int j = 0; j < 4; ++j) {
                    acc[i][j] = __builtin_amdgcn_mfma_f32_16x16x32_bf16(
                        ah[i], bh[j], acc[i][j], 0, 0, 0);
                    acc[i][j] = __builtin_amdgcn_mfma_f32_16x16x32_bf16(
                        ah[i], bl[j], acc[i][j], 0, 0, 0);
                    acc[i][j] = __builtin_amdgcn_mfma_f32_16x16x32_bf16(
                        al[i], bh[j], acc[i][j], 0, 0, 0);
                }
        }
    }

    #pragma unroll
    for (int i = 0; i < 4; ++i) {
        int r0 = m0 + wm + i * 16 + fq * 4;
        #pragma unroll
        for (int j = 0; j < 4; ++j) {
            int cc = n0 + wn + j * 16 + fr;
            if (cc < N) {
                #pragma unroll
                for (int r = 0; r < 4; ++r)
                    C[(size_t)(r0 + r) * N + cc] = acc[i][j][r];
            }
        }
    }
}

// ---------------------------------------------------------------------------
// conv_in as GEMM, 64x128 tile -> grid (2,128) = 256 blocks (fills all CUs).
// Register-prefetch pipelined; K-step accumulation order identical.
// ---------------------------------------------------------------------------
__global__ __launch_bounds__(256) void gemm_ci_kernel(
    const unsigned short* __restrict__ Ah, const unsigned short* __restrict__ Al,
    const unsigned short* __restrict__ Bh, const unsigned short* __restrict__ Bl,
    const float* __restrict__ bias,
    unsigned short* __restrict__ Ch, unsigned short* __restrict__ Cl)
{
    const int K = 512;
    __shared__ __align__(16) unsigned short AsH[64][40];
    __shared__ __align__(16) unsigned short AsL[64][40];
    __shared__ __align__(16) unsigned short BsH[128][40];
    __shared__ __align__(16) unsigned short BsL[128][40];

    int m0 = blockIdx.y * 64, n0 = blockIdx.x * 128;
    int b = m0 >> 11;
    size_t abase = ((size_t)b * LPAD + (m0 & 2047)) * IN_DIM;
    int t = threadIdx.x;
    int wid = t >> 6, lane = t & 63;
    int wm = (wid >> 1) * 32, wn = (wid & 1) * 64;
    int fr = lane & 15, fq = lane >> 4;
    int rr = t >> 2, q = t & 3;

    f32x4 z4 = {0.f, 0.f, 0.f, 0.f};
    f32x4 acc[2][4];
    #pragma unroll
    for (int i = 0; i < 2; ++i)
        #pragma unroll
        for (int j = 0; j < 4; ++j) acc[i][j] = z4;

    float4 rAh, rAl, rBh0, rBh1, rBl0, rBl1;
    auto ld = [&](int k0) {
        int koff = k0 + q * 8;
        rAh = *(const float4*)(Ah + abase + (size_t)rr * IN_DIM + koff);
        rAl = *(const float4*)(Al + abase + (size_t)rr * IN_DIM + koff);
        rBh0 = *(const float4*)(Bh + (size_t)(n0 + rr) * K + koff);
        rBh1 = *(const float4*)(Bh + (size_t)(n0 + rr + 64) * K + koff);
        rBl0 = *(const float4*)(Bl + (size_t)(n0 + rr) * K + koff);
        rBl1 = *(const float4*)(Bl + (size_t)(n0 + rr + 64) * K + koff);
    };
    ld(0);

    for (int k0 = 0; k0 < K; k0 += 32) {
        __syncthreads();
        *(float4*)&AsH[rr][q * 8] = rAh;
        *(float4*)&AsL[rr][q * 8] = rAl;
        *(float4*)&BsH[rr][q * 8] = rBh0;
        *(float4*)&BsH[rr + 64][q * 8] = rBh1;
        *(float4*)&BsL[rr][q * 8] = rBl0;
        *(float4*)&BsL[rr + 64][q * 8] = rBl1;
        __syncthreads();
        if (k0 + 32 < K) ld(k0 + 32);

        short8 ah[2], al[2], bh[4], bl[4];
        #pragma unroll
        for (int i = 0; i < 2; ++i) {
            ah[i] = *(const short8*)&AsH[wm + i * 16 + fr][fq * 8];
            al[i] = *(const short8*)&AsL[wm + i * 16 + fr][fq * 8];
        }
        #pragma unroll
        for (int j = 0; j < 4; ++j) {
            bh[j] = *(const short8*)&BsH[wn + j * 16 + fr][fq * 8];
            bl[j] = *(const short8*)&BsL[wn + j * 16 + fr][fq * 8];
        }
        #pragma unroll
        for (int i = 0; i < 2; ++i)
            #pragma unroll
            for (int j = 0; j < 4; ++j) {
                acc[i][j] = __builtin_amdgcn_mfma_f32_16x16x32_bf16(
                    ah[i], bh[j], acc[i][j], 0, 0, 0);
                acc[i][j] = __builtin_amdgcn_mfma_f32_16x16x32_bf16(
                    ah[i], bl[j], acc[i][j], 0, 0, 0);
                acc[i][j] = __builtin_amdgcn_mfma_f32_16x16x32_bf16(
                    al[i], bh[j], acc[i][j], 0, 0, 0);
            }
    }

    #pragma unroll
    for (int i = 0; i < 2; ++i) {
        int r0 = m0 + wm + i * 16 + fq * 4;
        #pragma unroll
        for (int j = 0; j < 4; ++j) {
            int cc = n0 + wn + j * 16 + fr;
            float bc = bias[cc];
            #pragma unroll
            for (int r = 0; r < 4; ++r) {
                float v = acc[i][j][r] + bc;
                unsigned short h = f2bf(v);
                size_t off = (size_t)(r0 + r) * D_MODEL + cc;
                Ch[off] = h;
                Cl[off] = f2bf(v - bf2f(h));
            }
        }
    }
}

// ---------------------------------------------------------------------------
// gemm2 (mamba_out), pure bf16, 64x128 tile -> grid (2,128) = 256 blocks.
// ---------------------------------------------------------------------------
__global__ __launch_bounds__(256) void gemm_mo_kernel(
    const unsigned short* __restrict__ Ah, const unsigned short* __restrict__ Bh,
    unsigned short* __restrict__ Ch)
{
    const int K = D_INNER;
    __shared__ __align__(16) unsigned short AsH[64][40];
    __shared__ __align__(16) unsigned short BsH[128][40];

    int m0 = blockIdx.y * 64, n0 = blockIdx.x * 128;
    int t = threadIdx.x;
    int wid = t >> 6, lane = t & 63;
    int wm = (wid >> 1) * 32, wn = (wid & 1) * 64;
    int fr = lane & 15, fq = lane >> 4;
    int rr = t >> 2, q = t & 3;

    f32x4 z4 = {0.f, 0.f, 0.f, 0.f};
    f32x4 acc[2][4];
    #pragma unroll
    for (int i = 0; i < 2; ++i)
        #pragma unroll
        for (int j = 0; j < 4; ++j) acc[i][j] = z4;

    float4 rA, rB0, rB1;
    auto ld = [&](int k0) {
        int koff = k0 + q * 8;
        rA  = *(const float4*)(Ah + (size_t)(m0 + rr) * K + koff);
        rB0 = *(const float4*)(Bh + (size_t)(n0 + rr) * K + koff);
        rB1 = *(const float4*)(Bh + (size_t)(n0 + rr + 64) * K + koff);
    };
    ld(0);

    for (int k0 = 0; k0 < K; k0 += 32) {
        __syncthreads();
        *(float4*)&AsH[rr][q * 8] = rA;
        *(float4*)&BsH[rr][q * 8] = rB0;
        *(float4*)&BsH[rr + 64][q * 8] = rB1;
        __syncthreads();
        if (k0 + 32 < K) ld(k0 + 32);

        short8 ah[2], bh[4];
        #pragma unroll
        for (int i = 0; i < 2; ++i)
            ah[i] = *(const short8*)&AsH[wm + i * 16 + fr][fq * 8];
        #pragma unroll
        for (int j = 0; j < 4; ++j)
            bh[j] = *(const short8*)&BsH[wn + j * 16 + fr][fq * 8];
        #pragma unroll
        for (int i = 0; i < 2; ++i)
            #pragma unroll
            for (int j = 0; j < 4; ++j)
                acc[i][j] = __builtin_amdgcn_mfma_f32_16x16x32_bf16(
                    ah[i], bh[j], acc[i][j], 0, 0, 0);
    }

    int b = m0 >> 11;
    #pragma unroll
    for (int i = 0; i < 2; ++i) {
        int r0 = m0 + wm + i * 16 + fq * 4;
        #pragma unroll
        for (int j = 0; j < 4; ++j) {
            int cc = n0 + wn + j * 16 + fr;
            #pragma unroll
            for (int r = 0; r < 4; ++r) {
                int l = (r0 + r) & 2047;
                size_t off = ((size_t)b * LPAD + l + 1) * D_MODEL + cc;
                Ch[off] = f2bf(acc[i][j][r]);
            }
        }
    }
}

// ---------------------------------------------------------------------------
// conv_out as GEMM, 64x64 tile -> grid (2,128) = 256 blocks.
// LDS-staged epilogue: stores 64B-contiguous along L.
// ---------------------------------------------------------------------------
__global__ __launch_bounds__(256) void gemm_co_kernel(
    const unsigned short* __restrict__ Ah, const unsigned short* __restrict__ Bh,
    float* __restrict__ out)
{
    const int K = 1024;
    __shared__ __align__(16) unsigned short AsH[64][40];
    __shared__ __align__(16) unsigned short BsH[64][40];
    __shared__ __align__(16) float outT[64][68];   // [cc_local][lr_local]

    int m0 = blockIdx.y * 64, n0 = blockIdx.x * 64;
    int b = m0 >> 11, l0t = m0 & 2047;
    size_t abase = ((size_t)b * LPAD + l0t) * D_MODEL;
    int t = threadIdx.x;
    int wid = t >> 6, lane = t & 63;
    int wm = (wid >> 1) * 32, wn = (wid & 1) * 32;
    int fr = lane & 15, fq = lane >> 4;
    int rr = t >> 2, q = t & 3;

    f32x4 z4 = {0.f, 0.f, 0.f, 0.f};
    f32x4 acc[2][2];
    #pragma unroll
    for (int i = 0; i < 2; ++i)
        #pragma unroll
        for (int j = 0; j < 2; ++j) acc[i][j] = z4;

    float4 rA, rB;
    auto ld = [&](int k0) {
        int koff = k0 + q * 8;
        rA = *(const float4*)(Ah + abase + (size_t)rr * D_MODEL + koff);
        rB = *(const float4*)(Bh + (size_t)(n0 + rr) * K + koff);
    };
    ld(0);

    for (int k0 = 0; k0 < K; k0 += 32) {
        __syncthreads();
        *(float4*)&AsH[rr][q * 8] = rA;
        *(float4*)&BsH[rr][q * 8] = rB;
        __syncthreads();
        if (k0 + 32 < K) ld(k0 + 32);

        short8 ah[2], bh[2];
        #pragma unroll
        for (int i = 0; i < 2; ++i)
            ah[i] = *(const short8*)&AsH[wm + i * 16 + fr][fq * 8];
        #pragma unroll
        for (int j = 0; j < 2; ++j)
            bh[j] = *(const short8*)&BsH[wn + j * 16 + fr][fq * 8];
        #pragma unroll
        for (int i = 0; i < 2; ++i)
            #pragma unroll
            for (int j = 0; j < 2; ++j)
                acc[i][j] = __builtin_amdgcn_mfma_f32_16x16x32_bf16(
                    ah[i], bh[j], acc[i][j], 0, 0, 0);
    }

    // epilogue: transpose through LDS; stores 64B-contiguous along L
    #pragma unroll
    for (int i = 0; i < 2; ++i)
        #pragma unroll
        for (int j = 0; j < 2; ++j)
            *(float4*)&outT[wn + j * 16 + fr][wm + i * 16 + fq * 4] =
                make_float4(acc[i][j][0], acc[i][j][1],
                            acc[i][j][2], acc[i][j][3]);
    __syncthreads();
    #pragma unroll
    for (int e = 0; e < 4; ++e) {
        int idx = e * 256 + t;
        int rowl = idx >> 4, colp = (idx & 15) * 4;
        float* dst = out + ((size_t)(b * OUT_DIM + n0 + rowl)) * L_ + l0t + colp;
        *(float4*)dst = *(const float4*)&outT[rowl][colp];
    }
}

// ---------------------------------------------------------------------------
// K4: causal depthwise conv + bias + SiLU. 8 l-values per thread.
// ---------------------------------------------------------------------------
__global__ __launch_bounds__(256) void dwconv_kernel(
    const float* __restrict__ zx, const float* __restrict__ w,
    const float* __restrict__ bias, float* __restrict__ xBCs)
{
    int idx = blockIdx.x * 256 + threadIdx.x;   // over B * L/8 * 800
    int c   = idx % CONV_DIM;
    int bl8 = idx / CONV_DIM;
    int b  = bl8 >> 8;               // L/8 = 256
    int l0 = (bl8 & 255) * 8;
    float4 wv = *(const float4*)&w[c * 4];
    float bi = bias[c];
    const float* base = zx + ((size_t)(b * L_ + l0)) * D_IN_PROJ + D_INNER + c;
    float r[11];
    #pragma unroll
    for (int k = 0; k < 11; ++k) {
        int l = l0 - 3 + k;
        r[k] = (l >= 0) ? base[(ptrdiff_t)(k - 3) * D_IN_PROJ] : 0.f;
    }
    #pragma unroll
    for (int i = 0; i < 8; ++i) {
        float acc = bi;
        acc = fmaf(r[i + 0], wv.x, acc);
        acc = fmaf(r[i + 1], wv.y, acc);
        acc = fmaf(r[i + 2], wv.z, acc);
        acc = fmaf(r[i + 3], wv.w, acc);
        float s = acc / (1.f + expf(-acc));
        xBCs[((size_t)(b * L_ + l0 + i)) * CONV_DIM + c] = s;
    }
}

// ---------------------------------------------------------------------------
// XCD-locality swizzle: all 32 hg blocks of one (b,c) share bid%8 -> same XCD
// bid = (bc>>3)<<8 | hg<<3 | (bc&7);  bc = b*32+c.
// ---------------------------------------------------------------------------
__device__ __forceinline__ void scan_decode(int bid, int& b, int& c, int& hg)
{
    int bcl = bid & 7;
    hg = (bid >> 3) & 31;
    int bc = ((bid >> 8) << 3) | bcl;
    c = bc & 31;
    b = bc >> 5;
}

// ---------------------------------------------------------------------------
// K5a+K5g merged: blocks 0..127 compute G[i][j] = C_i . B_j per (b,chunk)
// (bid%8 XCD mapping preserved); blocks 128.. run chunk-local state build.
// ---------------------------------------------------------------------------
__global__ __launch_bounds__(512) void scan_local2g(
    const float* __restrict__ xBCs, const float* __restrict__ zx,
    const float* __restrict__ dt_bias, const float* __restrict__ A_log,
    float* __restrict__ Sloc, float* __restrict__ prodA,
    float* __restrict__ dtb, float* __restrict__ G)
{
    int bid = blockIdx.x;
    int t = threadIdx.x;
    if (bid < 128) {
        // ---- gmat part (uses threads 0..255) ----
        __shared__ float Bs[64][16];
        __shared__ float Csg[64][16];
        int c = bid & 31, b = bid >> 5;
        int row0 = b * L_ + c * SCAN_CL;
        if (t < 256) {
            int j = t >> 2, q = t & 3;
            const float* r = xBCs + (size_t)(row0 + j) * CONV_DIM + D_INNER;
            *(float4*)&Bs[j][q * 4] = *(const float4*)(r + q * 4);
            *(float4*)&Csg[j][q * 4] = *(const float4*)(r + D_STATE + q * 4);
        }
        __syncthreads();
        if (t < 256) {
            int i = t >> 2, jq = t & 3;
            float4 c0 = *(const float4*)&Csg[i][0];
            float4 c1 = *(const float4*)&Csg[i][4];
            float4 c2 = *(const float4*)&Csg[i][8];
            float4 c3 = *(const float4*)&Csg[i][12];
            float dot[16];
            #pragma unroll
            for (int jj = 0; jj < 16; ++jj) {
                int j = jq * 16 + jj;
                float4 b0 = *(const float4*)&Bs[j][0];
                float4 b1 = *(const float4*)&Bs[j][4];
                float4 b2 = *(const float4*)&Bs[j][8];
                float4 b3 = *(const float4*)&Bs[j][12];
                float d = c0.x * b0.x + c0.y * b0.y + c0.z * b0.z + c0.w * b0.w;
                d = fmaf(c1.x, b1.x, d); d = fmaf(c1.y, b1.y, d);
                d = fmaf(c1.z, b1.z, d); d = fmaf(c1.w, b1.w, d);
                d = fmaf(c2.x, b2.x, d); d = fmaf(c2.y, b2.y, d);
                d = fmaf(c2.z, b2.z, d); d = fmaf(c2.w, b2.w, d);
                d = fmaf(c3.x, b3.x, d); d = fmaf(c3.y, b3.y, d);
                d = fmaf(c3.z, b3.z, d); d = fmaf(c3.w, b3.w, d);
                dot[jj] = d;
            }
            float* gout = G + ((size_t)bid * 64 + i) * 64 + jq * 16;
            #pragma unroll
            for (int q = 0; q < 4; ++q)
                *(float4*)(gout + q * 4) =
                    make_float4(dot[q*4], dot[q*4+1], dot[q*4+2], dot[q*4+3]);
        }
        return;
    }

    // ---- scan_local2 part ----
    __shared__ float  BsT[16][68];                      // [n][row], padded
    __shared__ __align__(16) float4 PkC4L[8][66];       // (pkx,pky,pkz,dtv)
    __shared__ float  UT[8][3][64];
    int b, c, hg;
    scan_decode(bid - 128, b, c, hg);
    int h0 = hg * 8;
    int row0 = b * L_ + c * SCAN_CL;

    if (t < 256) {   // B tile (coalesced)
        int j = t >> 2, q = t & 3;
        const float* r = xBCs + (size_t)(row0 + j) * CONV_DIM;
        float4 bv = *(const float4*)(r + D_INNER + q * 4);
        BsT[q*4+0][j] = bv.x; BsT[q*4+1][j] = bv.y;
        BsT[q*4+2][j] = bv.z; BsT[q*4+3][j] = bv.w;
    }
    {   // Pk staging: one entry per thread; fused softplus; single b128 write
        int hh = t & 7, j = t >> 3;
        float v = zx[(size_t)(row0 + j) * D_IN_PROJ + DT_START + h0 + hh]
                  + dt_bias[h0 + hh];
        float dtv = (v > 20.f) ? v : log1pf(expf(v));
        dtb[(size_t)(row0 + j) * NHEADS + h0 + hh] = dtv;   // spill for scan_final2
        const float* xr = xBCs + (size_t)(row0 + j) * CONV_DIM + (h0 + hh) * 3;
        PkC4L[hh][j] = make_float4(dtv * xr[0], dtv * xr[1], dtv * xr[2], dtv);
    }
    __syncthreads();

    int wv = t >> 6, lane = t & 63;
    int hh = wv;
    int hhu = __builtin_amdgcn_readfirstlane(wv);
    int p = lane >> 4, n = lane & 15;
    int pc = (p < 3) ? p : 2;

    float4 own = PkC4L[hh][lane];
    float pkx = own.x, pky = own.y, pkz = own.z, pkw = own.w;
    float A = -__expf(A_log[h0 + hhu]);
    float cum = pkw * A;
    #pragma unroll
    for (int off = 1; off < 64; off <<= 1) {
        float sv = __shfl_up(cum, off);
        if (lane >= off) cum += sv;
    }
    float cum63 = __shfl(cum, 63);
    float wf = __expf(cum63 - cum);
    UT[hh][0][lane] = wf * pkx;
    UT[hh][1][lane] = wf * pky;
    UT[hh][2][lane] = wf * pkz;
    float state = 0.f;
    #pragma unroll
    for (int q = 0; q < 16; ++q) {
        float4 Bv = *(const float4*)&BsT[n][q * 4];
        float4 Uv = *(const float4*)&UT[hh][pc][q * 4];
        state = fmaf(Uv.x, Bv.x, state);
        state = fmaf(Uv.y, Bv.y, state);
        state = fmaf(Uv.z, Bv.z, state);
        state = fmaf(Uv.w, Bv.w, state);
    }
    size_t bh = (size_t)(b * NHEADS + h0 + hh);
    if (p < 3) Sloc[(bh * SCAN_NC + c) * 48 + p * 16 + n] = state;
    if (lane == 0) prodA[bh * SCAN_NC + c] = __expf(cum63);
}

// ---------------------------------------------------------------------------
// K5b: sequential prefix over chunks, in place on Sloc
// ---------------------------------------------------------------------------
__global__ __launch_bounds__(256) void scan_prefix_kernel(
    float* __restrict__ Sloc, const float* __restrict__ prodA)
{
    int wv   = blockIdx.x * 4 + (threadIdx.x >> 6);
    int lane = threadIdx.x & 63;
    int p = lane >> 4, n = lane & 15;
    bool act = (p < 3);
    int l48 = ((p < 3) ? p : 2) * 16 + n;
    size_t base = (size_t)wv * SCAN_NC;

    float cur = 0.f;
    for (int c = 0; c < SCAN_NC; ++c) {
        float s  = Sloc[(base + c) * 48 + l48];
        float pa = prodA[base + c];
        if (act) Sloc[(base + c) * 48 + l48] = cur;
        cur = fmaf(pa, cur, s);
    }
}

// ---------------------------------------------------------------------------
// K5c: chunk-matmul final scan (unchanged).
// ---------------------------------------------------------------------------
__global__ __launch_bounds__(512) void scan_final2(
    const float* __restrict__ xBCs, const float* __restrict__ dtb,
    const float* __restrict__ A_log, const float* __restrict__ Dp,
    const float* __restrict__ Sinit, const float* __restrict__ G,
    float* __restrict__ y)
{
    __shared__ __align__(16) float4 PkC4[8][67];  // slot(j)=j+(j>>4)
    __shared__ float XWx[8][64];                  // wj*pkx (broadcast reads)
    __shared__ float XWy[8][64];
    __shared__ float XWz[8][64];
    __shared__ __align__(16) float Cs[64][36];    // [row][n], stride 36
    union GsYsr {
        float gs[64][64];                         // G tile, XOR-swizzled cols
        float ysr[64][25];                        // epilogue buffer (aliased)
    };
    __shared__ __align__(16) GsYsr Us;
    int b, c, hg;
    scan_decode(blockIdx.x, b, c, hg);
    int h0 = hg * 8;
    int t = threadIdx.x;
    int row0 = b * L_ + c * SCAN_CL;

    {   // Pk staging: one (head,row) per thread, single b128 LDS write
        int hh = t & 7, j = t >> 3;
        float dtv = dtb[(size_t)(row0 + j) * NHEADS + h0 + hh];
        const float* xr = xBCs + (size_t)(row0 + j) * CONV_DIM + (h0 + hh) * 3;
        PkC4[hh][j + (j >> 4)] =
            make_float4(dtv * xr[0], dtv * xr[1], dtv * xr[2], dtv);
    }
    if (t < 256) {   // C tile: coalesced global float4, b128 LDS write
        int j = t >> 2, q = t & 3;
        const float* r = xBCs + (size_t)(row0 + j) * CONV_DIM + D_INNER + D_STATE;
        *(float4*)&Cs[j][q * 4] = *(const float4*)(r + q * 4);
    }
    {   // G staging: 1024 float4 coalesced global reads, XOR-swizzled store
        const float* Gsrc = G + (size_t)(b * SCAN_NC + c) * 4096;
        #pragma unroll
        for (int e = 0; e < 2; ++e) {
            int idx = e * 512 + t;              // float4 index 0..1023
            int row = idx >> 4, cq = (idx & 15) * 4;
            *(float4*)&Us.gs[row][cq ^ ((row & 7) << 2)] =
                *(const float4*)(Gsrc + (size_t)idx * 4);
        }
    }
    __syncthreads();

    int wv = t >> 6, lane = t & 63;
    int hh = wv;
    int hhu = __builtin_amdgcn_readfirstlane(wv);   // SGPR wave id
    int I = lane >> 4;
    int sw = (lane & 7) << 2;                       // Gs read swizzle

    float4 own = PkC4[hh][lane + (lane >> 4)];
    float pkx = own.x, pky = own.y, pkz = own.z, pkw = own.w;

    // wave-uniform scalar loads (SMEM pipe): Sin row, A, D
    const float* sinp = Sinit +
        ((size_t)(b * NHEADS + h0 + hhu) * SCAN_NC + c) * 48;
    float A = -__expf(A_log[h0 + hhu]);
    float Dh = Dp[h0 + hhu];

    float cum = pkw * A;
    #pragma unroll
    for (int off = 1; off < 64; off <<= 1) {
        float sv = __shfl_up(cum, off);
        if (lane >= off) cum += sv;
    }
    float e0 = __shfl(cum, 15);
    float e1 = __shfl(cum, 31);
    float e2 = __shfl(cum, 47);
    float e3 = __shfl(cum, 63);
    int ia = (I << 4) - 1;
    float AIr = __shfl(cum, ia < 0 ? 0 : ia);
    float AI = (I == 0) ? 0.f : AIr;
    float ri = __expf(cum - AI);
    float Eo = (I == 0) ? e0 : (I == 1) ? e1 : (I == 2) ? e2 : e3;
    float wj = __expf(Eo - cum);
    XWx[hh][lane] = wj * pkx;
    XWy[hh][lane] = wj * pky;
    XWz[hh][lane] = wj * pkz;
    PkC4[hh][lane + (lane >> 4)].w = cum;        // publish cum_j (wave-local)
    float S0 = (I > 0) ? __expf(AI - e0) : 0.f;
    float S1 = (I > 1) ? __expf(AI - e1) : 0.f;
    float S2 = (I > 2) ? __expf(AI - e2) : 0.f;
    float ecum = __expf(cum);

    // per-lane C row (4 conflict-free b128 LDS reads)
    float4 c0 = *(const float4*)&Cs[lane][0];
    float4 c1 = *(const float4*)&Cs[lane][4];
    float4 c2 = *(const float4*)&Cs[lane][8];
    float4 c3 = *(const float4*)&Cs[lane][12];

    // initial-state part: s_p = sum_n C[lane][n] * Sin[p][n]  (Sin uniform)
    float s0, s1, s2;
    {
        s0 = c0.x*sinp[0];  s0 = fmaf(c0.y,sinp[1],s0);  s0 = fmaf(c0.z,sinp[2],s0);  s0 = fmaf(c0.w,sinp[3],s0);
        s0 = fmaf(c1.x,sinp[4],s0);  s0 = fmaf(c1.y,sinp[5],s0);  s0 = fmaf(c1.z,sinp[6],s0);  s0 = fmaf(c1.w,sinp[7],s0);
        s0 = fmaf(c2.x,sinp[8],s0);  s0 = fmaf(c2.y,sinp[9],s0);  s0 = fmaf(c2.z,sinp[10],s0); s0 = fmaf(c2.w,sinp[11],s0);
        s0 = fmaf(c3.x,sinp[12],s0); s0 = fmaf(c3.y,sinp[13],s0); s0 = fmaf(c3.z,sinp[14],s0); s0 = fmaf(c3.w,sinp[15],s0);
        s1 = c0.x*sinp[16]; s1 = fmaf(c0.y,sinp[17],s1); s1 = fmaf(c0.z,sinp[18],s1); s1 = fmaf(c0.w,sinp[19],s1);
        s1 = fmaf(c1.x,sinp[20],s1); s1 = fmaf(c1.y,sinp[21],s1); s1 = fmaf(c1.z,sinp[22],s1); s1 = fmaf(c1.w,sinp[23],s1);
        s1 = fmaf(c2.x,sinp[24],s1); s1 = fmaf(c2.y,sinp[25],s1); s1 = fmaf(c2.z,sinp[26],s1); s1 = fmaf(c2.w,sinp[27],s1);
        s1 = fmaf(c3.x,sinp[28],s1); s1 = fmaf(c3.y,sinp[29],s1); s1 = fmaf(c3.z,sinp[30],s1); s1 = fmaf(c3.w,sinp[31],s1);
        s2 = c0.x*sinp[32]; s2 = fmaf(c0.y,sinp[33],s2); s2 = fmaf(c0.z,sinp[34],s2); s2 = fmaf(c0.w,sinp[35],s2);
        s2 = fmaf(c1.x,sinp[36],s2); s2 = fmaf(c1.y,sinp[37],s2); s2 = fmaf(c1.z,sinp[38],s2); s2 = fmaf(c1.w,sinp[39],s2);
        s2 = fmaf(c2.x,sinp[40],s2); s2 = fmaf(c2.y,sinp[41],s2); s2 = fmaf(c2.z,sinp[42],s2); s2 = fmaf(c2.w,sinp[43],s2);
        s2 = fmaf(c3.x,sinp[44],s2); s2 = fmaf(c3.y,sinp[45],s2); s2 = fmaf(c3.z,sinp[46],s2); s2 = fmaf(c3.w,sinp[47],s2);
    }

    // J < I blocks: t_J = sum_kk Gs[lane][16J+kk] * xw_kk ; acc += S_J * t_J
    float acc0 = 0.f, acc1 = 0.f, acc2 = 0.f;
    #pragma unroll
    for (int J = 0; J < 3; ++J) {
        float SJ = (J == 0) ? S0 : (J == 1) ? S1 : S2;
        float t0 = 0.f, t1 = 0.f, t2 = 0.f;
        #pragma unroll
        for (int q = 0; q < 4; ++q) {
            float4 g4 = *(const float4*)&Us.gs[lane][(J * 16 + q * 4) ^ sw];
            float4 ux = *(const float4*)&XWx[hh][J * 16 + q * 4];
            float4 uy = *(const float4*)&XWy[hh][J * 16 + q * 4];
            float4 uz = *(const float4*)&XWz[hh][J * 16 + q * 4];
            t0 = fmaf(g4.x, ux.x, t0); t1 = fmaf(g4.x, uy.x, t1); t2 = fmaf(g4.x, uz.x, t2);
            t0 = fmaf(g4.y, ux.y, t0); t1 = fmaf(g4.y, uy.y, t1); t2 = fmaf(g4.y, uz.y, t2);
            t0 = fmaf(g4.z, ux.z, t0); t1 = fmaf(g4.z, uy.z, t1); t2 = fmaf(g4.z, uz.z, t2);
            t0 = fmaf(g4.w, ux.w, t0); t1 = fmaf(g4.w, uy.w, t1); t2 = fmaf(g4.w, uz.w, t2);
        }
        acc0 = fmaf(SJ, t0, acc0);
        acc1 = fmaf(SJ, t1, acc1);
        acc2 = fmaf(SJ, t2, acc2);
    }

    // diagonal block (J == I): masked, exp(cum_i - cum_j) <= 1 always
    float d0 = 0.f, d1 = 0.f, d2 = 0.f;
    const float4* pkr = &PkC4[hh][I * 17];
    int lr = lane & 15;
    #pragma unroll
    for (int q = 0; q < 4; ++q) {
        float4 g4 = *(const float4*)&Us.gs[lane][((I << 4) + q * 4) ^ sw];
        #pragma unroll
        for (int k = 0; k < 4; ++k) {
            int kk = q * 4 + k;
            float4 p4 = pkr[kk];
            float gk = (k == 0) ? g4.x : (k == 1) ? g4.y : (k == 2) ? g4.z : g4.w;
            float e = __expf(cum - p4.w);
            float mg = (kk <= lr) ? e * gk : 0.f;
            d0 = fmaf(mg, p4.x, d0);
            d1 = fmaf(mg, p4.y, d1);
            d2 = fmaf(mg, p4.z, d2);
        }
    }

    float rdt = 1.0f / pkw;
    float y0 = fmaf(ri, acc0, d0) + fmaf(ecum, s0, Dh * (pkx * rdt));
    float y1 = fmaf(ri, acc1, d1) + fmaf(ecum, s1, Dh * (pky * rdt));
    float y2 = fmaf(ri, acc2, d2) + fmaf(ecum, s2, Dh * (pkz * rdt));

    __syncthreads();     // all waves done reading Gs before ysr aliases it
    {
        float* yr = &Us.ysr[lane][hh * 3];
        yr[0] = y0; yr[1] = y1; yr[2] = y2;
    }
    __syncthreads();

    {   // coalesced epilogue: 24 contiguous channels per row
        int i2 = t >> 3, q2 = t & 7;
        float* dst = y + (size_t)(row0 + i2) * D_INNER + hg * 24 + q2 * 3;
        dst[0] = Us.ysr[i2][q2 * 3 + 0];
        dst[1] = Us.ysr[i2][q2 * 3 + 1];
        dst[2] = Us.ysr[i2][q2 * 3 + 2];
    }
}

// ---------------------------------------------------------------------------
// K6: y = y * silu(z); RMSNorm over 768; * norm_w.  Writes plain bf16 output.
// ---------------------------------------------------------------------------
__global__ __launch_bounds__(256) void gate_norm_kernel(
    const float* __restrict__ zx, const float* __restrict__ norm_w,
    const float* __restrict__ y, unsigned short* __restrict__ yh)
{
    int bl = blockIdx.x;
    int t  = threadIdx.x;
    const float* zrow = zx + (size_t)bl * D_IN_PROJ;
    const float* yrow = y + (size_t)bl * D_INNER;

    float v[3];
    float ss = 0.f;
    #pragma unroll
    for (int j = 0; j < 3; ++j) {
        int i = t + j * 256;
        float z = zrow[i];
        float s = z / (1.f + expf(-z));
        float val = yrow[i] * s;
        v[j] = val;
        ss += val * val;
    }
    ss += __shfl_xor(ss, 32);
    ss += __shfl_xor(ss, 16);
    ss += __shfl_xor(ss, 8);
    ss += __shfl_xor(ss, 4);
    ss += __shfl_xor(ss, 2);
    ss += __shfl_xor(ss, 1);
    __shared__ float red[4];
    int lane = t & 63, wid = t >> 6;
    if (lane == 0) red[wid] = ss;
    __syncthreads();
    float tot = red[0] + red[1] + red[2] + red[3];
    float rs = rsqrtf(tot * (1.f / D_INNER) + 1e-5f);
    #pragma unroll
    for (int j = 0; j < 3; ++j) {
        int i = t + j * 256;
        float o = v[j] * rs * norm_w[i];
        yh[(size_t)bl * D_INNER + i] = f2bf(o);
    }
}

// ---------------------------------------------------------------------------
extern "C" void kernel_launch(void* const* d_in, const int* in_sizes, int n_in,
                              void* d_out, int out_size, void* d_ws, size_t ws_size,
                              hipStream_t stream)
{
    const float* x           = (const float*)d_in[0];
    const float* conv_w      = (const float*)d_in[1];
    const float* conv_b      = (const float*)d_in[2];
    const float* in_proj_w   = (const float*)d_in[3];
    const float* dw_conv_w   = (const float*)d_in[4];
    const float* dw_conv_b   = (const float*)d_in[5];
    const float* dt_bias     = (const float*)d_in[6];
    const float* A_log       = (const float*)d_in[7];
    const float* Dp          = (const float*)d_in[8];
    const float* norm_w      = (const float*)d_in[9];
    const float* mamba_out_w = (const float*)d_in[10];
    const float* out_conv_w  = (const float*)d_in[11];
    float* out = (float*)d_out;
    float* ws  = (float*)d_ws;

    // ---- workspace layout (floats; ws = 256 MiB, we use ~133 MB) ----
    float* S0   = ws;                        //  2,097,152  Gbuf+Sloc
    float* zx   = S0 + 2097152;              // 14,942,208  early: xT+cw / zx
    float* xBCs = zx + 14942208;             //  6,553,600  early: ipw / xBCs, yb
    float* dtb  = xBCs + 6553600;            //  2,097,152  dtv spill
    float* ybuf = dtb + 2097152;             //  6,291,456  early: prodA+u / y
    float* tmpPf = ybuf + 6291456;           //  1,050,112  padded bf16 tmpP
    float* mowf  = tmpPf + 1050112;          //    196,608  mow hi+lo
    float* cowf  = mowf + 196608;            //     65,536  cow hi

    float* Gbuf = S0;                        // 524,288
    float* Sloc = S0 + 524288;               // 1,572,864

    unsigned short* xT_hi = (unsigned short*)zx;
    unsigned short* xT_lo = (unsigned short*)(zx + 525056);
    unsigned short* cw_hi = (unsigned short*)(zx + 1050112);
    unsigned short* cw_lo = (unsigned short*)(zx + 1115648);

    unsigned short* ipw_hi = (unsigned short*)xBCs;
    unsigned short* ipw_lo = (unsigned short*)(xBCs + 233472);
    unsigned short* yb_hi  = (unsigned short*)xBCs;            // after scan_final

    float* prodA = ybuf;
    unsigned short* u_hi = (unsigned short*)(ybuf + 32768);
    unsigned short* u_lo = (unsigned short*)(ybuf + 32768 + 1048576);

    unsigned short* tmpP_hi = (unsigned short*)tmpPf;          // 2,100,224 ush
    unsigned short* mow_hi  = (unsigned short*)mowf;           //   196,608 ush
    unsigned short* mow_lo  = (unsigned short*)(mowf + 98304); //   196,608 ush
    unsigned short* cow_hi  = (unsigned short*)cowf;           //   131,072 ush

    // ---- 1. ALL prep (early + late weights) in ONE launch ----
    prep_all_kernel<<<2714, 256, 0, stream>>>(
        xT_hi, xT_lo, conv_w, cw_hi, cw_lo, x, in_proj_w, ipw_hi, ipw_lo,
        out_conv_w, cow_hi, tmpP_hi, mamba_out_w, mow_hi, mow_lo);

    // ---- 2. conv_in as GEMM (64x128 tiles, 256 blocks) ----
    gemm_ci_kernel<<<dim3(2, (B_ * L_) / 64), 256, 0, stream>>>(
        xT_hi, xT_lo, cw_hi, cw_lo, conv_b, u_hi, u_lo);

    // ---- 3. in_proj GEMM (selective precision) ----
    gemm_ip2_kernel<<<dim3((D_IN_PROJ + 127) / 128, (B_ * L_) / 128), 256, 0, stream>>>(
        u_hi, u_lo, ipw_hi, ipw_lo, zx, B_ * L_, D_IN_PROJ, D_MODEL);

    // ---- 4. elementwise + scan ----
    dwconv_kernel<<<(B_ * (L_ / 8) * CONV_DIM) / 256, 256, 0, stream>>>(
        zx, dw_conv_w, dw_conv_b, xBCs);
    scan_local2g<<<128 + B_ * SCAN_NC * (NHEADS / 8), 512, 0, stream>>>(
        xBCs, zx, dt_bias, A_log, Sloc, prodA, dtb, Gbuf);
    scan_prefix_kernel<<<(B_ * NHEADS) / 4, 256, 0, stream>>>(Sloc, prodA);
    scan_final2<<<B_ * SCAN_NC * (NHEADS / 8), 512, 0, stream>>>(
        xBCs, dtb, A_log, Dp, Sloc, Gbuf, ybuf);

    // ---- 5. gate + norm (reads zx z-cols; last use of zx) -> bf16 yb ----
    gate_norm_kernel<<<B_ * L_, 256, 0, stream>>>(zx, norm_w, ybuf, yb_hi);

    // ---- 6. mamba_out GEMM (64x128 tiles, 256 blocks) -> padded bf16 tmpP ----
    gemm_mo_kernel<<<dim3(2, (B_ * L_) / 64), 256, 0, stream>>>(
        yb_hi, mow_hi, tmpP_hi);

    // ---- 7. conv_out as GEMM (64x64 tiles, 256 blocks, coalesced stores) ----
    gemm_co_kernel<<<dim3(OUT_DIM / 64, (B_ * L_) / 64), 256, 0, stream>>>(
        tmpP_hi, cow_hi, out);
}